// Round 1
// baseline (1502.130 us; speedup 1.0000x reference)
//
#include <hip/hip_runtime.h>
#include <hip/hip_bf16.h>
#include <math.h>

// Problem constants
#define BB 2
#define SS 2048
#define DD 1024
#define HH 16
#define HD 64

// ---------------------------------------------------------------------------
// GEMM config: 128x128 tile, BK=8, 256 threads, 8x8 per thread (2x2 of 4x4)
// ---------------------------------------------------------------------------
#define BM 128
#define BN 128
#define BKK 8

// Fused QKV projection:
//   out_sel[b,h,s,e] = sum_d X[b,s,d] * W_sel[h,d,e] + b_sel[h,e]
// viewed as GEMM: M = B*S = 4096 rows, N = 3*H*HD = 3072 cols (sel-major).
__global__ __launch_bounds__(256) void qkv_gemm(
    const float* __restrict__ X,
    const float* __restrict__ Wq, const float* __restrict__ bq,
    const float* __restrict__ Wk, const float* __restrict__ bk,
    const float* __restrict__ Wv, const float* __restrict__ bv,
    float* __restrict__ qo, float* __restrict__ ko, float* __restrict__ vo)
{
    __shared__ __align__(16) float As[BKK][BM + 4];  // stored transposed: As[k][m]
    __shared__ __align__(16) float Bs[BKK][BN + 4];  // Bs[k][n]

    const int tid = threadIdx.x;
    const int m0 = blockIdx.y * BM;
    const int n0 = blockIdx.x * BN;

    // A staging coords: thread loads X[m0+am][kt+ak .. +3] (float4)
    const int am = tid >> 1;          // 0..127
    const int ak = (tid & 1) * 4;     // 0 or 4
    // B staging coords: thread loads W[kt+bkr][n0+bn .. +3] (float4)
    const int bkr = tid >> 5;         // 0..7
    const int bn  = (tid & 31) * 4;   // 0..124

    // Precompute B global base pointer (sel/h/e fixed per thread; only k varies)
    const int n4  = n0 + bn;
    const int sel = n4 >> 10;
    const int hh  = (n4 >> 6) & 15;
    const int ee  = n4 & 63;
    const float* Wsel = (sel == 0) ? Wq : ((sel == 1) ? Wk : Wv);
    const float* Bp = Wsel + (size_t)hh * (DD * HD) + ee;   // + k*64
    const float* Ap = X + (size_t)(m0 + am) * DD + ak;      // + kt

    float4 aReg = *(const float4*)(Ap);
    float4 bReg = *(const float4*)(Bp + (size_t)bkr * HD);

    float acc[8][8];
#pragma unroll
    for (int i = 0; i < 8; i++)
#pragma unroll
        for (int j = 0; j < 8; j++) acc[i][j] = 0.0f;

    const int tm = (tid >> 4) * 4;   // 0..60
    const int tn = (tid & 15) * 4;   // 0..60

    for (int kt = 0; kt < DD; kt += BKK) {
        // store staged regs to LDS
        As[ak + 0][am] = aReg.x;
        As[ak + 1][am] = aReg.y;
        As[ak + 2][am] = aReg.z;
        As[ak + 3][am] = aReg.w;
        *(float4*)&Bs[bkr][bn] = bReg;
        __syncthreads();
        // prefetch next tiles
        if (kt + BKK < DD) {
            aReg = *(const float4*)(Ap + kt + BKK);
            bReg = *(const float4*)(Bp + (size_t)(kt + BKK + bkr) * HD);
        }
#pragma unroll
        for (int kk = 0; kk < BKK; kk++) {
            float4 a0 = *(const float4*)&As[kk][tm];
            float4 a1 = *(const float4*)&As[kk][tm + 64];
            float4 b0 = *(const float4*)&Bs[kk][tn];
            float4 b1 = *(const float4*)&Bs[kk][tn + 64];
            float ar[8] = {a0.x, a0.y, a0.z, a0.w, a1.x, a1.y, a1.z, a1.w};
            float br[8] = {b0.x, b0.y, b0.z, b0.w, b1.x, b1.y, b1.z, b1.w};
#pragma unroll
            for (int i = 0; i < 8; i++)
#pragma unroll
                for (int j = 0; j < 8; j++)
                    acc[i][j] = fmaf(ar[i], br[j], acc[i][j]);
        }
        __syncthreads();
    }

    // epilogue: add bias, scatter to q/k/v in [B,H,S,HD] layout
#pragma unroll
    for (int i = 0; i < 8; i++) {
        const int ml = (i < 4) ? (tm + i) : (64 + tm + i - 4);
        const int m = m0 + ml;
        const int b = m >> 11;          // / S
        const int s = m & (SS - 1);
#pragma unroll
        for (int half = 0; half < 2; half++) {
            const int n = n0 + half * 64 + tn;
            const int sl = n >> 10;
            const int h = (n >> 6) & 15;
            const int e = n & 63;
            const float* bias = (sl == 0) ? bq : ((sl == 1) ? bk : bv);
            float* op = (sl == 0) ? qo : ((sl == 1) ? ko : vo);
            float4 val;
            val.x = acc[i][half * 4 + 0] + bias[h * HD + e + 0];
            val.y = acc[i][half * 4 + 1] + bias[h * HD + e + 1];
            val.z = acc[i][half * 4 + 2] + bias[h * HD + e + 2];
            val.w = acc[i][half * 4 + 3] + bias[h * HD + e + 3];
            *(float4*)&op[(((size_t)b * HH + h) * SS + s) * HD + e] = val;
        }
    }
}

// Output projection: out[m, n] = sum_k ctx[m, k] * Wo[k, n] + bo[n]
__global__ __launch_bounds__(256) void out_gemm(
    const float* __restrict__ Ctx, const float* __restrict__ Wo,
    const float* __restrict__ bo, float* __restrict__ out)
{
    __shared__ __align__(16) float As[BKK][BM + 4];
    __shared__ __align__(16) float Bs[BKK][BN + 4];

    const int tid = threadIdx.x;
    const int m0 = blockIdx.y * BM;
    const int n0 = blockIdx.x * BN;

    const int am = tid >> 1;
    const int ak = (tid & 1) * 4;
    const int bkr = tid >> 5;
    const int bn  = (tid & 31) * 4;

    const float* Bp = Wo + (size_t)(n0 + bn);           // + k*1024
    const float* Ap = Ctx + (size_t)(m0 + am) * DD + ak;

    float4 aReg = *(const float4*)(Ap);
    float4 bReg = *(const float4*)(Bp + (size_t)bkr * DD);

    float acc[8][8];
#pragma unroll
    for (int i = 0; i < 8; i++)
#pragma unroll
        for (int j = 0; j < 8; j++) acc[i][j] = 0.0f;

    const int tm = (tid >> 4) * 4;
    const int tn = (tid & 15) * 4;

    for (int kt = 0; kt < DD; kt += BKK) {
        As[ak + 0][am] = aReg.x;
        As[ak + 1][am] = aReg.y;
        As[ak + 2][am] = aReg.z;
        As[ak + 3][am] = aReg.w;
        *(float4*)&Bs[bkr][bn] = bReg;
        __syncthreads();
        if (kt + BKK < DD) {
            aReg = *(const float4*)(Ap + kt + BKK);
            bReg = *(const float4*)(Bp + (size_t)(kt + BKK + bkr) * DD);
        }
#pragma unroll
        for (int kk = 0; kk < BKK; kk++) {
            float4 a0 = *(const float4*)&As[kk][tm];
            float4 a1 = *(const float4*)&As[kk][tm + 64];
            float4 b0 = *(const float4*)&Bs[kk][tn];
            float4 b1 = *(const float4*)&Bs[kk][tn + 64];
            float ar[8] = {a0.x, a0.y, a0.z, a0.w, a1.x, a1.y, a1.z, a1.w};
            float br[8] = {b0.x, b0.y, b0.z, b0.w, b1.x, b1.y, b1.z, b1.w};
#pragma unroll
            for (int i = 0; i < 8; i++)
#pragma unroll
                for (int j = 0; j < 8; j++)
                    acc[i][j] = fmaf(ar[i], br[j], acc[i][j]);
        }
        __syncthreads();
    }

#pragma unroll
    for (int i = 0; i < 8; i++) {
        const int ml = (i < 4) ? (tm + i) : (64 + tm + i - 4);
        const size_t m = (size_t)(m0 + ml);
#pragma unroll
        for (int half = 0; half < 2; half++) {
            const int n = n0 + half * 64 + tn;
            float4 val;
            val.x = acc[i][half * 4 + 0] + bo[n + 0];
            val.y = acc[i][half * 4 + 1] + bo[n + 1];
            val.z = acc[i][half * 4 + 2] + bo[n + 2];
            val.w = acc[i][half * 4 + 3] + bo[n + 3];
            *(float4*)&out[m * DD + n] = val;
        }
    }
}

// ---------------------------------------------------------------------------
// Flash attention: block = 256 threads (4 waves), one (b,h) x 64-row Q tile.
// Wave w owns Q rows [w*16, w*16+16); lane owns score-col j / ctx-dim e.
// ---------------------------------------------------------------------------
#define TQ 64
#define TK 64

__global__ __launch_bounds__(256) void attn_kernel(
    const float* __restrict__ q, const float* __restrict__ k,
    const float* __restrict__ v, float* __restrict__ ctx)
{
    __shared__ __align__(16) float Qs[TQ][HD];       // [64][64]
    __shared__ __align__(16) float Kt[HD][TK + 1];   // transposed, +1 pad
    __shared__ __align__(16) float Vs[TK][HD];
    __shared__ __align__(16) float Ps[TQ][TK];       // wave-private rows

    const int tid = threadIdx.x;
    const int lane = tid & 63;
    const int w = tid >> 6;
    const int bh = blockIdx.y;           // b*H + h
    const int q0 = blockIdx.x * TQ;

    const float* qp = q + (size_t)bh * SS * HD;
    const float* kp = k + (size_t)bh * SS * HD;
    const float* vp = v + (size_t)bh * SS * HD;

    // load Q tile (64x64 floats, coalesced float4)
#pragma unroll
    for (int it = 0; it < 4; it++) {
        int idx = tid + it * 256;        // 0..1023
        int row = idx >> 4;
        int c4 = (idx & 15) * 4;
        *(float4*)&Qs[row][c4] = *(const float4*)&qp[(size_t)(q0 + row) * HD + c4];
    }

    float m_r[16], l_r[16], o_r[16];
#pragma unroll
    for (int r = 0; r < 16; r++) {
        m_r[r] = -INFINITY; l_r[r] = 0.0f; o_r[r] = 0.0f;
    }
    const float scale = 0.125f;   // 1/sqrt(64)

    for (int t = 0; t < SS / TK; t++) {
        __syncthreads();   // prior tile's compute done before overwrite
        // load K (transposed) and V tiles
#pragma unroll
        for (int it = 0; it < 4; it++) {
            int idx = tid + it * 256;
            int row = idx >> 4;
            int c4 = (idx & 15) * 4;
            float4 kv4 = *(const float4*)&kp[(size_t)(t * TK + row) * HD + c4];
            Kt[c4 + 0][row] = kv4.x;
            Kt[c4 + 1][row] = kv4.y;
            Kt[c4 + 2][row] = kv4.z;
            Kt[c4 + 3][row] = kv4.w;
            *(float4*)&Vs[row][c4] = *(const float4*)&vp[(size_t)(t * TK + row) * HD + c4];
        }
        __syncthreads();

        // scores: sc[r] = dot(Q[w*16+r], K[lane])
        float sc[16];
#pragma unroll
        for (int r = 0; r < 16; r++) sc[r] = 0.0f;
        for (int d4 = 0; d4 < 16; d4++) {
            float k0 = Kt[4 * d4 + 0][lane];
            float k1 = Kt[4 * d4 + 1][lane];
            float k2 = Kt[4 * d4 + 2][lane];
            float k3 = Kt[4 * d4 + 3][lane];
#pragma unroll
            for (int r = 0; r < 16; r++) {
                float4 qv = *(const float4*)&Qs[w * 16 + r][4 * d4];
                sc[r] = fmaf(qv.x, k0, fmaf(qv.y, k1, fmaf(qv.z, k2, fmaf(qv.w, k3, sc[r]))));
            }
        }

        // online softmax per row (wave-wide reductions; all lanes get results)
#pragma unroll
        for (int r = 0; r < 16; r++) {
            float s_ = sc[r] * scale;
            float mt = s_;
            for (int off = 32; off > 0; off >>= 1)
                mt = fmaxf(mt, __shfl_xor(mt, off));
            float mn = fmaxf(m_r[r], mt);
            float p = __expf(s_ - mn);
            float ps = p;
            for (int off = 32; off > 0; off >>= 1)
                ps += __shfl_xor(ps, off);
            float alpha = __expf(m_r[r] - mn);
            l_r[r] = l_r[r] * alpha + ps;
            m_r[r] = mn;
            o_r[r] *= alpha;
            Ps[w * 16 + r][lane] = p;
        }

        // PV: o[r] += sum_j P[w*16+r][j] * V[j][lane]   (wave-local Ps)
        for (int j4 = 0; j4 < 16; j4++) {
            float v0 = Vs[4 * j4 + 0][lane];
            float v1 = Vs[4 * j4 + 1][lane];
            float v2 = Vs[4 * j4 + 2][lane];
            float v3 = Vs[4 * j4 + 3][lane];
#pragma unroll
            for (int r = 0; r < 16; r++) {
                float4 p4 = *(const float4*)&Ps[w * 16 + r][4 * j4];
                o_r[r] = fmaf(p4.x, v0, fmaf(p4.y, v1, fmaf(p4.z, v2, fmaf(p4.w, v3, o_r[r]))));
            }
        }
    }

    // write ctx in [B,S,D] layout (head-concat): ctx[b][s][h*64 + lane]
    const int b = bh >> 4;
    const int h = bh & 15;
#pragma unroll
    for (int r = 0; r < 16; r++) {
        const int srow = q0 + w * 16 + r;
        ctx[((size_t)b * SS + srow) * DD + h * HD + lane] = o_r[r] / l_r[r];
    }
}

// ---------------------------------------------------------------------------
extern "C" void kernel_launch(void* const* d_in, const int* in_sizes, int n_in,
                              void* d_out, int out_size, void* d_ws, size_t ws_size,
                              hipStream_t stream) {
    const float* X  = (const float*)d_in[0];
    const float* Wq = (const float*)d_in[1];
    const float* bq = (const float*)d_in[2];
    const float* Wk = (const float*)d_in[3];
    const float* bk = (const float*)d_in[4];
    const float* Wv = (const float*)d_in[5];
    const float* bv = (const float*)d_in[6];
    const float* Wo = (const float*)d_in[7];
    const float* bo = (const float*)d_in[8];
    float* out = (float*)d_out;

    float* ws = (float*)d_ws;
    const size_t NEL = (size_t)BB * HH * SS * HD;   // 4194304
    float* qws = ws;
    float* kws = ws + NEL;
    float* vws = ws + 2 * NEL;
    float* cws = ws + 3 * NEL;

    // 1) fused QKV projection: M=4096, N=3072
    qkv_gemm<<<dim3(3072 / BN, 4096 / BM), 256, 0, stream>>>(
        X, Wq, bq, Wk, bk, Wv, bv, qws, kws, vws);

    // 2) flash attention: (S/TQ, B*H) blocks
    attn_kernel<<<dim3(SS / TQ, BB * HH), 256, 0, stream>>>(qws, kws, vws, cws);

    // 3) output projection: M=4096, N=1024
    out_gemm<<<dim3(1024 / BN, 4096 / BM), 256, 0, stream>>>(cws, Wo, bo, out);
}

// Round 2
// 646.329 us; speedup vs baseline: 2.3241x; 2.3241x over previous
//
#include <hip/hip_runtime.h>
#include <hip/hip_bf16.h>
#include <math.h>

// Problem constants
#define BB 2
#define SS 2048
#define DD 1024
#define HH 16
#define HD 64

typedef __attribute__((ext_vector_type(8))) short bf16x8;
typedef __attribute__((ext_vector_type(4))) float f32x4;

__device__ __forceinline__ unsigned short f2bf(float f) {
    __hip_bfloat16 h = __float2bfloat16(f);
    union { __hip_bfloat16 h; unsigned short s; } r;
    r.h = h;
    return r.s;
}
__device__ __forceinline__ float bf2f(unsigned short s) {
    union { unsigned short s; __hip_bfloat16 h; } r;
    r.s = s;
    return __bfloat162float(r.h);
}

// ---------------------------------------------------------------------------
// GEMM config: 128x128 tile, BK=8, 256 threads, 8x8 per thread (2x2 of 4x4)
// ---------------------------------------------------------------------------
#define BM 128
#define BN 128
#define BKK 8

__global__ __launch_bounds__(256) void qkv_gemm(
    const float* __restrict__ X,
    const float* __restrict__ Wq, const float* __restrict__ bq,
    const float* __restrict__ Wk, const float* __restrict__ bk,
    const float* __restrict__ Wv, const float* __restrict__ bv,
    float* __restrict__ qo, float* __restrict__ ko, float* __restrict__ vo)
{
    __shared__ __align__(16) float As[BKK][BM + 4];
    __shared__ __align__(16) float Bs[BKK][BN + 4];

    const int tid = threadIdx.x;
    const int m0 = blockIdx.y * BM;
    const int n0 = blockIdx.x * BN;

    const int am = tid >> 1;
    const int ak = (tid & 1) * 4;
    const int bkr = tid >> 5;
    const int bn  = (tid & 31) * 4;

    const int n4  = n0 + bn;
    const int sel = n4 >> 10;
    const int hh  = (n4 >> 6) & 15;
    const int ee  = n4 & 63;
    const float* Wsel = (sel == 0) ? Wq : ((sel == 1) ? Wk : Wv);
    const float* Bp = Wsel + (size_t)hh * (DD * HD) + ee;
    const float* Ap = X + (size_t)(m0 + am) * DD + ak;

    float4 aReg = *(const float4*)(Ap);
    float4 bReg = *(const float4*)(Bp + (size_t)bkr * HD);

    float acc[8][8];
#pragma unroll
    for (int i = 0; i < 8; i++)
#pragma unroll
        for (int j = 0; j < 8; j++) acc[i][j] = 0.0f;

    const int tm = (tid >> 4) * 4;
    const int tn = (tid & 15) * 4;

    for (int kt = 0; kt < DD; kt += BKK) {
        As[ak + 0][am] = aReg.x;
        As[ak + 1][am] = aReg.y;
        As[ak + 2][am] = aReg.z;
        As[ak + 3][am] = aReg.w;
        *(float4*)&Bs[bkr][bn] = bReg;
        __syncthreads();
        if (kt + BKK < DD) {
            aReg = *(const float4*)(Ap + kt + BKK);
            bReg = *(const float4*)(Bp + (size_t)(kt + BKK + bkr) * HD);
        }
#pragma unroll
        for (int kk = 0; kk < BKK; kk++) {
            float4 a0 = *(const float4*)&As[kk][tm];
            float4 a1 = *(const float4*)&As[kk][tm + 64];
            float4 b0 = *(const float4*)&Bs[kk][tn];
            float4 b1 = *(const float4*)&Bs[kk][tn + 64];
            float ar[8] = {a0.x, a0.y, a0.z, a0.w, a1.x, a1.y, a1.z, a1.w};
            float br[8] = {b0.x, b0.y, b0.z, b0.w, b1.x, b1.y, b1.z, b1.w};
#pragma unroll
            for (int i = 0; i < 8; i++)
#pragma unroll
                for (int j = 0; j < 8; j++)
                    acc[i][j] = fmaf(ar[i], br[j], acc[i][j]);
        }
        __syncthreads();
    }

#pragma unroll
    for (int i = 0; i < 8; i++) {
        const int ml = (i < 4) ? (tm + i) : (64 + tm + i - 4);
        const int m = m0 + ml;
        const int b = m >> 11;
        const int s = m & (SS - 1);
#pragma unroll
        for (int half = 0; half < 2; half++) {
            const int n = n0 + half * 64 + tn;
            const int sl = n >> 10;
            const int h = (n >> 6) & 15;
            const int e = n & 63;
            const float* bias = (sl == 0) ? bq : ((sl == 1) ? bk : bv);
            float* op = (sl == 0) ? qo : ((sl == 1) ? ko : vo);
            float4 val;
            val.x = acc[i][half * 4 + 0] + bias[h * HD + e + 0];
            val.y = acc[i][half * 4 + 1] + bias[h * HD + e + 1];
            val.z = acc[i][half * 4 + 2] + bias[h * HD + e + 2];
            val.w = acc[i][half * 4 + 3] + bias[h * HD + e + 3];
            *(float4*)&op[(((size_t)b * HH + h) * SS + s) * HD + e] = val;
        }
    }
}

__global__ __launch_bounds__(256) void out_gemm(
    const float* __restrict__ Ctx, const float* __restrict__ Wo,
    const float* __restrict__ bo, float* __restrict__ out)
{
    __shared__ __align__(16) float As[BKK][BM + 4];
    __shared__ __align__(16) float Bs[BKK][BN + 4];

    const int tid = threadIdx.x;
    const int m0 = blockIdx.y * BM;
    const int n0 = blockIdx.x * BN;

    const int am = tid >> 1;
    const int ak = (tid & 1) * 4;
    const int bkr = tid >> 5;
    const int bn  = (tid & 31) * 4;

    const float* Bp = Wo + (size_t)(n0 + bn);
    const float* Ap = Ctx + (size_t)(m0 + am) * DD + ak;

    float4 aReg = *(const float4*)(Ap);
    float4 bReg = *(const float4*)(Bp + (size_t)bkr * DD);

    float acc[8][8];
#pragma unroll
    for (int i = 0; i < 8; i++)
#pragma unroll
        for (int j = 0; j < 8; j++) acc[i][j] = 0.0f;

    const int tm = (tid >> 4) * 4;
    const int tn = (tid & 15) * 4;

    for (int kt = 0; kt < DD; kt += BKK) {
        As[ak + 0][am] = aReg.x;
        As[ak + 1][am] = aReg.y;
        As[ak + 2][am] = aReg.z;
        As[ak + 3][am] = aReg.w;
        *(float4*)&Bs[bkr][bn] = bReg;
        __syncthreads();
        if (kt + BKK < DD) {
            aReg = *(const float4*)(Ap + kt + BKK);
            bReg = *(const float4*)(Bp + (size_t)(kt + BKK + bkr) * DD);
        }
#pragma unroll
        for (int kk = 0; kk < BKK; kk++) {
            float4 a0 = *(const float4*)&As[kk][tm];
            float4 a1 = *(const float4*)&As[kk][tm + 64];
            float4 b0 = *(const float4*)&Bs[kk][tn];
            float4 b1 = *(const float4*)&Bs[kk][tn + 64];
            float ar[8] = {a0.x, a0.y, a0.z, a0.w, a1.x, a1.y, a1.z, a1.w};
            float br[8] = {b0.x, b0.y, b0.z, b0.w, b1.x, b1.y, b1.z, b1.w};
#pragma unroll
            for (int i = 0; i < 8; i++)
#pragma unroll
                for (int j = 0; j < 8; j++)
                    acc[i][j] = fmaf(ar[i], br[j], acc[i][j]);
        }
        __syncthreads();
    }

#pragma unroll
    for (int i = 0; i < 8; i++) {
        const int ml = (i < 4) ? (tm + i) : (64 + tm + i - 4);
        const size_t m = (size_t)(m0 + ml);
#pragma unroll
        for (int half = 0; half < 2; half++) {
            const int n = n0 + half * 64 + tn;
            float4 val;
            val.x = acc[i][half * 4 + 0] + bo[n + 0];
            val.y = acc[i][half * 4 + 1] + bo[n + 1];
            val.z = acc[i][half * 4 + 2] + bo[n + 2];
            val.w = acc[i][half * 4 + 3] + bo[n + 3];
            *(float4*)&out[m * DD + n] = val;
        }
    }
}

// ---------------------------------------------------------------------------
// MFMA flash attention.
// Block = 256 threads (4 waves). Q tile = 128 rows (wave w: rows w*32..w*32+31,
// as 2 m-subtiles of 16). K tile = 64 keys. mfma_f32_16x16x32_bf16 with
// verified layouts: A[m=lane&15][k=quad*8+j], B[k=quad*8+j][n=lane&15],
// C/D[row=quad*4+reg][col=lane&15].
// QK^T in split-bf16 (QhiKhi + QloKhi + QhiKlo) for fp32-grade scores;
// PV in plain bf16. Q frags live in registers for the whole K loop.
// ---------------------------------------------------------------------------
#define TQB 128
#define TKB 64
#define KSTR 72   // LDS row stride (elems): 144 B, 16B-aligned for ds_read_b128

__global__ __launch_bounds__(256) void attn_mfma(
    const float* __restrict__ q, const float* __restrict__ k,
    const float* __restrict__ v, float* __restrict__ ctx)
{
    __shared__ __align__(16) unsigned short Khi[TKB * KSTR];
    __shared__ __align__(16) unsigned short Klo[TKB * KSTR];
    __shared__ __align__(16) unsigned short Vt [HD * KSTR];     // V transposed [e][kj]
    __shared__ __align__(16) unsigned short Ps [4][32 * KSTR];  // per-wave P

    const int tid  = threadIdx.x;
    const int lane = tid & 63;
    const int w    = tid >> 6;
    const int l15  = lane & 15;
    const int quad = lane >> 4;
    const int bh   = blockIdx.y;
    const int q0   = blockIdx.x * TQB;

    const float* qp = q + (size_t)bh * SS * HD;
    const float* kp = k + (size_t)bh * SS * HD;
    const float* vp = v + (size_t)bh * SS * HD;

    // ---- Q A-frags in registers (hi/lo split), held across the whole K loop
    bf16x8 qhi[2][2], qlo[2][2];
#pragma unroll
    for (int msub = 0; msub < 2; msub++) {
        const float* qrow = qp + (size_t)(q0 + w * 32 + msub * 16 + l15) * HD;
#pragma unroll
        for (int dstep = 0; dstep < 2; dstep++) {
#pragma unroll
            for (int j = 0; j < 8; j++) {
                float x = qrow[dstep * 32 + quad * 8 + j];
                unsigned short h = f2bf(x);
                unsigned short lo = f2bf(x - bf2f(h));
                qhi[msub][dstep][j] = (short)h;
                qlo[msub][dstep][j] = (short)lo;
            }
        }
    }

    float m_r[2][4], l_r[2][4];
    f32x4 o[2][4];
#pragma unroll
    for (int ms = 0; ms < 2; ms++)
#pragma unroll
        for (int r = 0; r < 4; r++) {
            m_r[ms][r] = -1e30f;
            l_r[ms][r] = 0.0f;
        }
#pragma unroll
    for (int ms = 0; ms < 2; ms++)
#pragma unroll
        for (int e = 0; e < 4; e++)
            o[ms][e] = (f32x4){0.0f, 0.0f, 0.0f, 0.0f};

    const float scale = 0.125f;  // 1/sqrt(64)
    const int rg = tid >> 4;     // V-transpose staging coords
    const int cg = tid & 15;

    for (int t = 0; t < SS / TKB; t++) {
        __syncthreads();  // previous tile's LDS reads complete

        // ---- stage K tile: bf16 hi/lo, layout [key][d], stride KSTR
        const float* kbase = kp + (size_t)t * TKB * HD;
#pragma unroll
        for (int it = 0; it < 4; it++) {
            int idx = tid + it * 256;
            int row = idx >> 4;
            int c4 = (idx & 15) * 4;
            float4 kv = *(const float4*)&kbase[(size_t)row * HD + c4];
            ushort4 h, lo;
            h.x = f2bf(kv.x); lo.x = f2bf(kv.x - bf2f(h.x));
            h.y = f2bf(kv.y); lo.y = f2bf(kv.y - bf2f(h.y));
            h.z = f2bf(kv.z); lo.z = f2bf(kv.z - bf2f(h.z));
            h.w = f2bf(kv.w); lo.w = f2bf(kv.w - bf2f(h.w));
            *(ushort4*)&Khi[row * KSTR + c4] = h;
            *(ushort4*)&Klo[row * KSTR + c4] = lo;
        }
        // ---- stage V tile transposed: Vt[e][kj], 4x4 register transpose
        const float* vbase = vp + (size_t)t * TKB * HD;
        float4 vv0 = *(const float4*)&vbase[(size_t)(rg * 4 + 0) * HD + cg * 4];
        float4 vv1 = *(const float4*)&vbase[(size_t)(rg * 4 + 1) * HD + cg * 4];
        float4 vv2 = *(const float4*)&vbase[(size_t)(rg * 4 + 2) * HD + cg * 4];
        float4 vv3 = *(const float4*)&vbase[(size_t)(rg * 4 + 3) * HD + cg * 4];
        {
            ushort4 tv;
            tv.x = f2bf(vv0.x); tv.y = f2bf(vv1.x); tv.z = f2bf(vv2.x); tv.w = f2bf(vv3.x);
            *(ushort4*)&Vt[(cg * 4 + 0) * KSTR + rg * 4] = tv;
            tv.x = f2bf(vv0.y); tv.y = f2bf(vv1.y); tv.z = f2bf(vv2.y); tv.w = f2bf(vv3.y);
            *(ushort4*)&Vt[(cg * 4 + 1) * KSTR + rg * 4] = tv;
            tv.x = f2bf(vv0.z); tv.y = f2bf(vv1.z); tv.z = f2bf(vv2.z); tv.w = f2bf(vv3.z);
            *(ushort4*)&Vt[(cg * 4 + 2) * KSTR + rg * 4] = tv;
            tv.x = f2bf(vv0.w); tv.y = f2bf(vv1.w); tv.z = f2bf(vv2.w); tv.w = f2bf(vv3.w);
            *(ushort4*)&Vt[(cg * 4 + 3) * KSTR + rg * 4] = tv;
        }
        __syncthreads();

        // ---- scores: sc[msub][ksub] = Q(32xd) x K^T, split-bf16
        f32x4 sc[2][4];
#pragma unroll
        for (int ksub = 0; ksub < 4; ksub++) {
            const int krow = (ksub * 16 + l15) * KSTR + quad * 8;
            bf16x8 kh0 = *(const bf16x8*)&Khi[krow];
            bf16x8 kh1 = *(const bf16x8*)&Khi[krow + 32];
            bf16x8 kl0 = *(const bf16x8*)&Klo[krow];
            bf16x8 kl1 = *(const bf16x8*)&Klo[krow + 32];
#pragma unroll
            for (int msub = 0; msub < 2; msub++) {
                f32x4 acc = (f32x4){0.0f, 0.0f, 0.0f, 0.0f};
                acc = __builtin_amdgcn_mfma_f32_16x16x32_bf16(qhi[msub][0], kh0, acc, 0, 0, 0);
                acc = __builtin_amdgcn_mfma_f32_16x16x32_bf16(qlo[msub][0], kh0, acc, 0, 0, 0);
                acc = __builtin_amdgcn_mfma_f32_16x16x32_bf16(qhi[msub][0], kl0, acc, 0, 0, 0);
                acc = __builtin_amdgcn_mfma_f32_16x16x32_bf16(qhi[msub][1], kh1, acc, 0, 0, 0);
                acc = __builtin_amdgcn_mfma_f32_16x16x32_bf16(qlo[msub][1], kh1, acc, 0, 0, 0);
                acc = __builtin_amdgcn_mfma_f32_16x16x32_bf16(qhi[msub][1], kl1, acc, 0, 0, 0);
                sc[msub][ksub] = acc;
            }
        }

        // ---- online softmax (rows = msub*16 + quad*4 + r; reduce over 16 lanes)
#pragma unroll
        for (int msub = 0; msub < 2; msub++) {
#pragma unroll
            for (int r = 0; r < 4; r++) {
                float s0 = sc[msub][0][r] * scale;
                float s1 = sc[msub][1][r] * scale;
                float s2 = sc[msub][2][r] * scale;
                float s3 = sc[msub][3][r] * scale;
                float mx = fmaxf(fmaxf(s0, s1), fmaxf(s2, s3));
                mx = fmaxf(mx, __shfl_xor(mx, 1));
                mx = fmaxf(mx, __shfl_xor(mx, 2));
                mx = fmaxf(mx, __shfl_xor(mx, 4));
                mx = fmaxf(mx, __shfl_xor(mx, 8));
                float mn = fmaxf(m_r[msub][r], mx);
                unsigned short b0 = f2bf(__expf(s0 - mn));
                unsigned short b1 = f2bf(__expf(s1 - mn));
                unsigned short b2 = f2bf(__expf(s2 - mn));
                unsigned short b3 = f2bf(__expf(s3 - mn));
                float ps = bf2f(b0) + bf2f(b1) + bf2f(b2) + bf2f(b3);
                ps += __shfl_xor(ps, 1);
                ps += __shfl_xor(ps, 2);
                ps += __shfl_xor(ps, 4);
                ps += __shfl_xor(ps, 8);
                float alpha = __expf(m_r[msub][r] - mn);
                m_r[msub][r] = mn;
                l_r[msub][r] = l_r[msub][r] * alpha + ps;
                o[msub][0][r] *= alpha;
                o[msub][1][r] *= alpha;
                o[msub][2][r] *= alpha;
                o[msub][3][r] *= alpha;
                const int prow = msub * 16 + quad * 4 + r;
                Ps[w][prow * KSTR +  0 + l15] = b0;
                Ps[w][prow * KSTR + 16 + l15] = b1;
                Ps[w][prow * KSTR + 32 + l15] = b2;
                Ps[w][prow * KSTR + 48 + l15] = b3;
            }
        }

        // ---- PV: o += P(32x64) x V(64x64)   (Ps is wave-private: no barrier)
#pragma unroll
        for (int kjstep = 0; kjstep < 2; kjstep++) {
            bf16x8 pa0 = *(const bf16x8*)&Ps[w][(0 + l15) * KSTR + kjstep * 32 + quad * 8];
            bf16x8 pa1 = *(const bf16x8*)&Ps[w][(16 + l15) * KSTR + kjstep * 32 + quad * 8];
#pragma unroll
            for (int esub = 0; esub < 4; esub++) {
                bf16x8 vb = *(const bf16x8*)&Vt[(esub * 16 + l15) * KSTR + kjstep * 32 + quad * 8];
                o[0][esub] = __builtin_amdgcn_mfma_f32_16x16x32_bf16(pa0, vb, o[0][esub], 0, 0, 0);
                o[1][esub] = __builtin_amdgcn_mfma_f32_16x16x32_bf16(pa1, vb, o[1][esub], 0, 0, 0);
            }
        }
    }

    // ---- epilogue: ctx[b][s][h*64 + e] = o / l
    const int b = bh >> 4;
    const int h = bh & 15;
#pragma unroll
    for (int msub = 0; msub < 2; msub++) {
#pragma unroll
        for (int r = 0; r < 4; r++) {
            const int row = q0 + w * 32 + msub * 16 + quad * 4 + r;
            const float inv_l = 1.0f / l_r[msub][r];
#pragma unroll
            for (int esub = 0; esub < 4; esub++) {
                ctx[((size_t)b * SS + row) * DD + h * HD + esub * 16 + l15] =
                    o[msub][esub][r] * inv_l;
            }
        }
    }
}

// ---------------------------------------------------------------------------
extern "C" void kernel_launch(void* const* d_in, const int* in_sizes, int n_in,
                              void* d_out, int out_size, void* d_ws, size_t ws_size,
                              hipStream_t stream) {
    const float* X  = (const float*)d_in[0];
    const float* Wq = (const float*)d_in[1];
    const float* bq = (const float*)d_in[2];
    const float* Wk = (const float*)d_in[3];
    const float* bk = (const float*)d_in[4];
    const float* Wv = (const float*)d_in[5];
    const float* bv = (const float*)d_in[6];
    const float* Wo = (const float*)d_in[7];
    const float* bo = (const float*)d_in[8];
    float* out = (float*)d_out;

    float* ws = (float*)d_ws;
    const size_t NEL = (size_t)BB * HH * SS * HD;   // 4194304
    float* qws = ws;
    float* kws = ws + NEL;
    float* vws = ws + 2 * NEL;
    float* cws = ws + 3 * NEL;

    // 1) fused QKV projection: M=4096, N=3072
    qkv_gemm<<<dim3(3072 / BN, 4096 / BM), 256, 0, stream>>>(
        X, Wq, bq, Wk, bk, Wv, bv, qws, kws, vws);

    // 2) MFMA flash attention: (S/128, B*H) blocks
    attn_mfma<<<dim3(SS / TQB, BB * HH), 256, 0, stream>>>(qws, kws, vws, cws);

    // 3) output projection: M=4096, N=1024
    out_gemm<<<dim3(1024 / BN, 4096 / BM), 256, 0, stream>>>(cws, Wo, bo, out);
}

// Round 3
// 395.688 us; speedup vs baseline: 3.7962x; 1.6334x over previous
//
#include <hip/hip_runtime.h>
#include <hip/hip_bf16.h>
#include <math.h>

// Problem constants
#define BB 2
#define SS 2048
#define DD 1024
#define HH 16
#define HD 64

typedef __attribute__((ext_vector_type(8))) short bf16x8;
typedef __attribute__((ext_vector_type(4))) float f32x4;

__device__ __forceinline__ unsigned short f2bf(float f) {
    __hip_bfloat16 h = __float2bfloat16(f);
    union { __hip_bfloat16 h; unsigned short s; } r;
    r.h = h;
    return r.s;
}
__device__ __forceinline__ float bf2f(unsigned short s) {
    union { unsigned short s; __hip_bfloat16 h; } r;
    r.s = s;
    return __bfloat162float(r.h);
}

// ---------------------------------------------------------------------------
// Split-bf16 MFMA GEMM: 128x128 tile, BK=32, 256 threads (4 waves, 2x2).
// Each wave computes 64x64 = 4x4 subtiles of mfma_f32_16x16x32_bf16.
// C = Ahi*Bhi + Alo*Bhi + Ahi*Blo  (fp32-grade accuracy, 3x MFMA cost).
// LDS layout: frag-contiguous chunks. Chunk = 16 rows x 32 k = 512 elems;
// elem (r,k) at chunk*512 + ((k>>3)*16 + r)*8 + (k&7). A fragment read is
// then a single conflict-free ds_read_b128 at chunk*1024B + lane*16B.
// ---------------------------------------------------------------------------
#define GBM 128
#define GBN 128
#define GBK 32

__device__ __forceinline__ void cvt_hilo4(const float* x, ushort4& h, ushort4& l) {
    h.x = f2bf(x[0]); l.x = f2bf(x[0] - bf2f(h.x));
    h.y = f2bf(x[1]); l.y = f2bf(x[1] - bf2f(h.y));
    h.z = f2bf(x[2]); l.z = f2bf(x[2] - bf2f(h.z));
    h.w = f2bf(x[3]); l.w = f2bf(x[3] - bf2f(h.w));
}

// Fused QKV projection: M = B*S = 4096, N = 3*H*HD = 3072 (sel-major cols).
__global__ __launch_bounds__(256) void qkv_gemm(
    const float* __restrict__ X,
    const float* __restrict__ Wq, const float* __restrict__ bq,
    const float* __restrict__ Wk, const float* __restrict__ bk,
    const float* __restrict__ Wv, const float* __restrict__ bv,
    float* __restrict__ qo, float* __restrict__ ko, float* __restrict__ vo)
{
    __shared__ __align__(16) unsigned short Ah[8 * 512];
    __shared__ __align__(16) unsigned short Al[8 * 512];
    __shared__ __align__(16) unsigned short Bh[8 * 512];
    __shared__ __align__(16) unsigned short Bl[8 * 512];

    const int tid = threadIdx.x;
    const int m0 = blockIdx.y * GBM;
    const int n0 = blockIdx.x * GBN;
    const int lane = tid & 63;
    const int w = tid >> 6;
    const int wm = w & 1, wn = w >> 1;
    const int l15 = lane & 15, quad = lane >> 4;

    // A staging: thread handles 4 rows x 4 cols at (am0, ak0)
    const int am0 = (tid >> 3) * 4;     // 0..124
    const int ak0 = (tid & 7) * 4;      // 0..28
    const float* Ap = X + (size_t)(m0 + am0) * DD + ak0;
    const int aLane = (am0 & 15) + 16 * (ak0 >> 3);   // base lane-slot (row offset added per r)
    const int aChunkBase = (am0 >> 4) * 512;
    const int aJ = ak0 & 7;

    // B staging: thread handles 4 k-rows x 4 n-cols at (bk0, bn0)
    const int bk0 = (tid >> 5) * 4;     // 0..28
    const int bn0 = (tid & 31) * 4;     // 0..124
    const int ng = n0 + bn0;
    const int sel = ng >> 10;
    const int hh  = (ng >> 6) & 15;
    const int ee  = ng & 63;
    const float* Wsel = (sel == 0) ? Wq : ((sel == 1) ? Wk : Wv);
    const float* Bp = Wsel + (size_t)hh * (DD * HD) + ee;   // + d*HD

    f32x4 acc[4][4];
#pragma unroll
    for (int i = 0; i < 4; i++)
#pragma unroll
        for (int j = 0; j < 4; j++) acc[i][j] = (f32x4){0.f, 0.f, 0.f, 0.f};

    for (int kt = 0; kt < DD; kt += GBK) {
        // global loads (fp32)
        float4 av[4], bv4[4];
#pragma unroll
        for (int r = 0; r < 4; r++)
            av[r] = *(const float4*)(Ap + (size_t)r * DD + kt);
#pragma unroll
        for (int r = 0; r < 4; r++)
            bv4[r] = *(const float4*)(Bp + (size_t)(kt + bk0 + r) * HD);

        __syncthreads();   // previous compute done before LDS overwrite

        // A: convert + store (rows natural: k runs along float4)
#pragma unroll
        for (int r = 0; r < 4; r++) {
            ushort4 h, l;
            cvt_hilo4((const float*)&av[r], h, l);
            const int addr = aChunkBase + (aLane + r) * 8 + aJ;
            *(ushort4*)&Ah[addr] = h;
            *(ushort4*)&Al[addr] = l;
        }
        // B: 4x4 register transpose (need k-contiguous per n), then store
#pragma unroll
        for (int c = 0; c < 4; c++) {
            float kv[4];
            kv[0] = ((const float*)&bv4[0])[c];
            kv[1] = ((const float*)&bv4[1])[c];
            kv[2] = ((const float*)&bv4[2])[c];
            kv[3] = ((const float*)&bv4[3])[c];
            ushort4 h, l;
            cvt_hilo4(kv, h, l);
            const int n = bn0 + c;
            const int addr = (n >> 4) * 512 + ((n & 15) + 16 * (bk0 >> 3)) * 8 + (bk0 & 7);
            *(ushort4*)&Bh[addr] = h;
            *(ushort4*)&Bl[addr] = l;
        }
        __syncthreads();

        // fragments + MFMA
        bf16x8 ah[4], al[4];
#pragma unroll
        for (int ms = 0; ms < 4; ms++) {
            const int ca = (wm * 4 + ms) * 512 + lane * 8;
            ah[ms] = *(const bf16x8*)&Ah[ca];
            al[ms] = *(const bf16x8*)&Al[ca];
        }
#pragma unroll
        for (int ns = 0; ns < 4; ns++) {
            const int cb = (wn * 4 + ns) * 512 + lane * 8;
            bf16x8 bh = *(const bf16x8*)&Bh[cb];
            bf16x8 bl = *(const bf16x8*)&Bl[cb];
#pragma unroll
            for (int ms = 0; ms < 4; ms++) {
                acc[ms][ns] = __builtin_amdgcn_mfma_f32_16x16x32_bf16(ah[ms], bh, acc[ms][ns], 0, 0, 0);
                acc[ms][ns] = __builtin_amdgcn_mfma_f32_16x16x32_bf16(al[ms], bh, acc[ms][ns], 0, 0, 0);
                acc[ms][ns] = __builtin_amdgcn_mfma_f32_16x16x32_bf16(ah[ms], bl, acc[ms][ns], 0, 0, 0);
            }
        }
    }

    // epilogue: bias + scatter to q/k/v [B,H,S,HD]
#pragma unroll
    for (int ms = 0; ms < 4; ms++) {
#pragma unroll
        for (int rr = 0; rr < 4; rr++) {
            const int m = m0 + wm * 64 + ms * 16 + quad * 4 + rr;
            const int b = m >> 11;
            const int s = m & (SS - 1);
#pragma unroll
            for (int ns = 0; ns < 4; ns++) {
                const int n = n0 + wn * 64 + ns * 16 + l15;
                const int sl = n >> 10;
                const int h = (n >> 6) & 15;
                const int e = n & 63;
                const float* bias = (sl == 0) ? bq : ((sl == 1) ? bk : bv);
                float* op = (sl == 0) ? qo : ((sl == 1) ? ko : vo);
                op[(((size_t)b * HH + h) * SS + s) * HD + e] = acc[ms][ns][rr] + bias[h * HD + e];
            }
        }
    }
}

// Output projection: out = ctx @ Wo + bo.  M=4096, N=1024, K=1024.
__global__ __launch_bounds__(256) void out_gemm(
    const float* __restrict__ Ctx, const float* __restrict__ Wo,
    const float* __restrict__ bo, float* __restrict__ out)
{
    __shared__ __align__(16) unsigned short Ah[8 * 512];
    __shared__ __align__(16) unsigned short Al[8 * 512];
    __shared__ __align__(16) unsigned short Bh[8 * 512];
    __shared__ __align__(16) unsigned short Bl[8 * 512];

    const int tid = threadIdx.x;
    const int m0 = blockIdx.y * GBM;
    const int n0 = blockIdx.x * GBN;
    const int lane = tid & 63;
    const int w = tid >> 6;
    const int wm = w & 1, wn = w >> 1;
    const int l15 = lane & 15, quad = lane >> 4;

    const int am0 = (tid >> 3) * 4;
    const int ak0 = (tid & 7) * 4;
    const float* Ap = Ctx + (size_t)(m0 + am0) * DD + ak0;
    const int aLane = (am0 & 15) + 16 * (ak0 >> 3);
    const int aChunkBase = (am0 >> 4) * 512;
    const int aJ = ak0 & 7;

    const int bk0 = (tid >> 5) * 4;
    const int bn0 = (tid & 31) * 4;
    const float* Bp = Wo + (size_t)(n0 + bn0);   // + k*DD

    f32x4 acc[4][4];
#pragma unroll
    for (int i = 0; i < 4; i++)
#pragma unroll
        for (int j = 0; j < 4; j++) acc[i][j] = (f32x4){0.f, 0.f, 0.f, 0.f};

    for (int kt = 0; kt < DD; kt += GBK) {
        float4 av[4], bv4[4];
#pragma unroll
        for (int r = 0; r < 4; r++)
            av[r] = *(const float4*)(Ap + (size_t)r * DD + kt);
#pragma unroll
        for (int r = 0; r < 4; r++)
            bv4[r] = *(const float4*)(Bp + (size_t)(kt + bk0 + r) * DD);

        __syncthreads();

#pragma unroll
        for (int r = 0; r < 4; r++) {
            ushort4 h, l;
            cvt_hilo4((const float*)&av[r], h, l);
            const int addr = aChunkBase + (aLane + r) * 8 + aJ;
            *(ushort4*)&Ah[addr] = h;
            *(ushort4*)&Al[addr] = l;
        }
#pragma unroll
        for (int c = 0; c < 4; c++) {
            float kv[4];
            kv[0] = ((const float*)&bv4[0])[c];
            kv[1] = ((const float*)&bv4[1])[c];
            kv[2] = ((const float*)&bv4[2])[c];
            kv[3] = ((const float*)&bv4[3])[c];
            ushort4 h, l;
            cvt_hilo4(kv, h, l);
            const int n = bn0 + c;
            const int addr = (n >> 4) * 512 + ((n & 15) + 16 * (bk0 >> 3)) * 8 + (bk0 & 7);
            *(ushort4*)&Bh[addr] = h;
            *(ushort4*)&Bl[addr] = l;
        }
        __syncthreads();

        bf16x8 ah[4], al[4];
#pragma unroll
        for (int ms = 0; ms < 4; ms++) {
            const int ca = (wm * 4 + ms) * 512 + lane * 8;
            ah[ms] = *(const bf16x8*)&Ah[ca];
            al[ms] = *(const bf16x8*)&Al[ca];
        }
#pragma unroll
        for (int ns = 0; ns < 4; ns++) {
            const int cb = (wn * 4 + ns) * 512 + lane * 8;
            bf16x8 bh = *(const bf16x8*)&Bh[cb];
            bf16x8 bl = *(const bf16x8*)&Bl[cb];
#pragma unroll
            for (int ms = 0; ms < 4; ms++) {
                acc[ms][ns] = __builtin_amdgcn_mfma_f32_16x16x32_bf16(ah[ms], bh, acc[ms][ns], 0, 0, 0);
                acc[ms][ns] = __builtin_amdgcn_mfma_f32_16x16x32_bf16(al[ms], bh, acc[ms][ns], 0, 0, 0);
                acc[ms][ns] = __builtin_amdgcn_mfma_f32_16x16x32_bf16(ah[ms], bl, acc[ms][ns], 0, 0, 0);
            }
        }
    }

#pragma unroll
    for (int ms = 0; ms < 4; ms++) {
#pragma unroll
        for (int rr = 0; rr < 4; rr++) {
            const size_t m = (size_t)(m0 + wm * 64 + ms * 16 + quad * 4 + rr);
#pragma unroll
            for (int ns = 0; ns < 4; ns++) {
                const int n = n0 + wn * 64 + ns * 16 + l15;
                out[m * DD + n] = acc[ms][ns][rr] + bo[n];
            }
        }
    }
}

// ---------------------------------------------------------------------------
// MFMA flash attention (unchanged from round 2; verified absmax 4.9e-4).
// ---------------------------------------------------------------------------
#define TQB 128
#define TKB 64
#define KSTR 72

__global__ __launch_bounds__(256) void attn_mfma(
    const float* __restrict__ q, const float* __restrict__ k,
    const float* __restrict__ v, float* __restrict__ ctx)
{
    __shared__ __align__(16) unsigned short Khi[TKB * KSTR];
    __shared__ __align__(16) unsigned short Klo[TKB * KSTR];
    __shared__ __align__(16) unsigned short Vt [HD * KSTR];
    __shared__ __align__(16) unsigned short Ps [4][32 * KSTR];

    const int tid  = threadIdx.x;
    const int lane = tid & 63;
    const int w    = tid >> 6;
    const int l15  = lane & 15;
    const int quad = lane >> 4;
    const int bh   = blockIdx.y;
    const int q0   = blockIdx.x * TQB;

    const float* qp = q + (size_t)bh * SS * HD;
    const float* kp = k + (size_t)bh * SS * HD;
    const float* vp = v + (size_t)bh * SS * HD;

    bf16x8 qhi[2][2], qlo[2][2];
#pragma unroll
    for (int msub = 0; msub < 2; msub++) {
        const float* qrow = qp + (size_t)(q0 + w * 32 + msub * 16 + l15) * HD;
#pragma unroll
        for (int dstep = 0; dstep < 2; dstep++) {
#pragma unroll
            for (int j = 0; j < 8; j++) {
                float x = qrow[dstep * 32 + quad * 8 + j];
                unsigned short h = f2bf(x);
                unsigned short lo = f2bf(x - bf2f(h));
                qhi[msub][dstep][j] = (short)h;
                qlo[msub][dstep][j] = (short)lo;
            }
        }
    }

    float m_r[2][4], l_r[2][4];
    f32x4 o[2][4];
#pragma unroll
    for (int ms = 0; ms < 2; ms++)
#pragma unroll
        for (int r = 0; r < 4; r++) {
            m_r[ms][r] = -1e30f;
            l_r[ms][r] = 0.0f;
        }
#pragma unroll
    for (int ms = 0; ms < 2; ms++)
#pragma unroll
        for (int e = 0; e < 4; e++)
            o[ms][e] = (f32x4){0.0f, 0.0f, 0.0f, 0.0f};

    const float scale = 0.125f;
    const int rg = tid >> 4;
    const int cg = tid & 15;

    for (int t = 0; t < SS / TKB; t++) {
        __syncthreads();

        const float* kbase = kp + (size_t)t * TKB * HD;
#pragma unroll
        for (int it = 0; it < 4; it++) {
            int idx = tid + it * 256;
            int row = idx >> 4;
            int c4 = (idx & 15) * 4;
            float4 kv = *(const float4*)&kbase[(size_t)row * HD + c4];
            ushort4 h, lo;
            h.x = f2bf(kv.x); lo.x = f2bf(kv.x - bf2f(h.x));
            h.y = f2bf(kv.y); lo.y = f2bf(kv.y - bf2f(h.y));
            h.z = f2bf(kv.z); lo.z = f2bf(kv.z - bf2f(h.z));
            h.w = f2bf(kv.w); lo.w = f2bf(kv.w - bf2f(h.w));
            *(ushort4*)&Khi[row * KSTR + c4] = h;
            *(ushort4*)&Klo[row * KSTR + c4] = lo;
        }
        const float* vbase = vp + (size_t)t * TKB * HD;
        float4 vv0 = *(const float4*)&vbase[(size_t)(rg * 4 + 0) * HD + cg * 4];
        float4 vv1 = *(const float4*)&vbase[(size_t)(rg * 4 + 1) * HD + cg * 4];
        float4 vv2 = *(const float4*)&vbase[(size_t)(rg * 4 + 2) * HD + cg * 4];
        float4 vv3 = *(const float4*)&vbase[(size_t)(rg * 4 + 3) * HD + cg * 4];
        {
            ushort4 tv;
            tv.x = f2bf(vv0.x); tv.y = f2bf(vv1.x); tv.z = f2bf(vv2.x); tv.w = f2bf(vv3.x);
            *(ushort4*)&Vt[(cg * 4 + 0) * KSTR + rg * 4] = tv;
            tv.x = f2bf(vv0.y); tv.y = f2bf(vv1.y); tv.z = f2bf(vv2.y); tv.w = f2bf(vv3.y);
            *(ushort4*)&Vt[(cg * 4 + 1) * KSTR + rg * 4] = tv;
            tv.x = f2bf(vv0.z); tv.y = f2bf(vv1.z); tv.z = f2bf(vv2.z); tv.w = f2bf(vv3.z);
            *(ushort4*)&Vt[(cg * 4 + 2) * KSTR + rg * 4] = tv;
            tv.x = f2bf(vv0.w); tv.y = f2bf(vv1.w); tv.z = f2bf(vv2.w); tv.w = f2bf(vv3.w);
            *(ushort4*)&Vt[(cg * 4 + 3) * KSTR + rg * 4] = tv;
        }
        __syncthreads();

        f32x4 sc[2][4];
#pragma unroll
        for (int ksub = 0; ksub < 4; ksub++) {
            const int krow = (ksub * 16 + l15) * KSTR + quad * 8;
            bf16x8 kh0 = *(const bf16x8*)&Khi[krow];
            bf16x8 kh1 = *(const bf16x8*)&Khi[krow + 32];
            bf16x8 kl0 = *(const bf16x8*)&Klo[krow];
            bf16x8 kl1 = *(const bf16x8*)&Klo[krow + 32];
#pragma unroll
            for (int msub = 0; msub < 2; msub++) {
                f32x4 acc = (f32x4){0.0f, 0.0f, 0.0f, 0.0f};
                acc = __builtin_amdgcn_mfma_f32_16x16x32_bf16(qhi[msub][0], kh0, acc, 0, 0, 0);
                acc = __builtin_amdgcn_mfma_f32_16x16x32_bf16(qlo[msub][0], kh0, acc, 0, 0, 0);
                acc = __builtin_amdgcn_mfma_f32_16x16x32_bf16(qhi[msub][0], kl0, acc, 0, 0, 0);
                acc = __builtin_amdgcn_mfma_f32_16x16x32_bf16(qhi[msub][1], kh1, acc, 0, 0, 0);
                acc = __builtin_amdgcn_mfma_f32_16x16x32_bf16(qlo[msub][1], kh1, acc, 0, 0, 0);
                acc = __builtin_amdgcn_mfma_f32_16x16x32_bf16(qhi[msub][1], kl1, acc, 0, 0, 0);
                sc[msub][ksub] = acc;
            }
        }

#pragma unroll
        for (int msub = 0; msub < 2; msub++) {
#pragma unroll
            for (int r = 0; r < 4; r++) {
                float s0 = sc[msub][0][r] * scale;
                float s1 = sc[msub][1][r] * scale;
                float s2 = sc[msub][2][r] * scale;
                float s3 = sc[msub][3][r] * scale;
                float mx = fmaxf(fmaxf(s0, s1), fmaxf(s2, s3));
                mx = fmaxf(mx, __shfl_xor(mx, 1));
                mx = fmaxf(mx, __shfl_xor(mx, 2));
                mx = fmaxf(mx, __shfl_xor(mx, 4));
                mx = fmaxf(mx, __shfl_xor(mx, 8));
                float mn = fmaxf(m_r[msub][r], mx);
                unsigned short b0 = f2bf(__expf(s0 - mn));
                unsigned short b1 = f2bf(__expf(s1 - mn));
                unsigned short b2 = f2bf(__expf(s2 - mn));
                unsigned short b3 = f2bf(__expf(s3 - mn));
                float ps = bf2f(b0) + bf2f(b1) + bf2f(b2) + bf2f(b3);
                ps += __shfl_xor(ps, 1);
                ps += __shfl_xor(ps, 2);
                ps += __shfl_xor(ps, 4);
                ps += __shfl_xor(ps, 8);
                float alpha = __expf(m_r[msub][r] - mn);
                m_r[msub][r] = mn;
                l_r[msub][r] = l_r[msub][r] * alpha + ps;
                o[msub][0][r] *= alpha;
                o[msub][1][r] *= alpha;
                o[msub][2][r] *= alpha;
                o[msub][3][r] *= alpha;
                const int prow = msub * 16 + quad * 4 + r;
                Ps[w][prow * KSTR +  0 + l15] = b0;
                Ps[w][prow * KSTR + 16 + l15] = b1;
                Ps[w][prow * KSTR + 32 + l15] = b2;
                Ps[w][prow * KSTR + 48 + l15] = b3;
            }
        }

#pragma unroll
        for (int kjstep = 0; kjstep < 2; kjstep++) {
            bf16x8 pa0 = *(const bf16x8*)&Ps[w][(0 + l15) * KSTR + kjstep * 32 + quad * 8];
            bf16x8 pa1 = *(const bf16x8*)&Ps[w][(16 + l15) * KSTR + kjstep * 32 + quad * 8];
#pragma unroll
            for (int esub = 0; esub < 4; esub++) {
                bf16x8 vb = *(const bf16x8*)&Vt[(esub * 16 + l15) * KSTR + kjstep * 32 + quad * 8];
                o[0][esub] = __builtin_amdgcn_mfma_f32_16x16x32_bf16(pa0, vb, o[0][esub], 0, 0, 0);
                o[1][esub] = __builtin_amdgcn_mfma_f32_16x16x32_bf16(pa1, vb, o[1][esub], 0, 0, 0);
            }
        }
    }

    const int b = bh >> 4;
    const int h = bh & 15;
#pragma unroll
    for (int msub = 0; msub < 2; msub++) {
#pragma unroll
        for (int r = 0; r < 4; r++) {
            const int row = q0 + w * 32 + msub * 16 + quad * 4 + r;
            const float inv_l = 1.0f / l_r[msub][r];
#pragma unroll
            for (int esub = 0; esub < 4; esub++) {
                ctx[((size_t)b * SS + row) * DD + h * HD + esub * 16 + l15] =
                    o[msub][esub][r] * inv_l;
            }
        }
    }
}

// ---------------------------------------------------------------------------
extern "C" void kernel_launch(void* const* d_in, const int* in_sizes, int n_in,
                              void* d_out, int out_size, void* d_ws, size_t ws_size,
                              hipStream_t stream) {
    const float* X  = (const float*)d_in[0];
    const float* Wq = (const float*)d_in[1];
    const float* bq = (const float*)d_in[2];
    const float* Wk = (const float*)d_in[3];
    const float* bk = (const float*)d_in[4];
    const float* Wv = (const float*)d_in[5];
    const float* bv = (const float*)d_in[6];
    const float* Wo = (const float*)d_in[7];
    const float* bo = (const float*)d_in[8];
    float* out = (float*)d_out;

    float* ws = (float*)d_ws;
    const size_t NEL = (size_t)BB * HH * SS * HD;   // 4194304
    float* qws = ws;
    float* kws = ws + NEL;
    float* vws = ws + 2 * NEL;
    float* cws = ws + 3 * NEL;

    // 1) fused QKV projection (split-bf16 MFMA): M=4096, N=3072
    qkv_gemm<<<dim3(3072 / GBN, 4096 / GBM), 256, 0, stream>>>(
        X, Wq, bq, Wk, bk, Wv, bv, qws, kws, vws);

    // 2) MFMA flash attention
    attn_mfma<<<dim3(SS / TQB, BB * HH), 256, 0, stream>>>(qws, kws, vws, cws);

    // 3) output projection (split-bf16 MFMA): M=4096, N=1024
    out_gemm<<<dim3(1024 / GBN, 4096 / GBM), 256, 0, stream>>>(cws, Wo, bo, out);
}

// Round 4
// 393.937 us; speedup vs baseline: 3.8131x; 1.0044x over previous
//
#include <hip/hip_runtime.h>
#include <hip/hip_bf16.h>
#include <math.h>

// Problem constants
#define BB 2
#define SS 2048
#define DD 1024
#define HH 16
#define HD 64

typedef __attribute__((ext_vector_type(8))) short bf16x8;
typedef __attribute__((ext_vector_type(4))) float f32x4;
typedef __attribute__((ext_vector_type(4))) unsigned short u16x4;

__device__ __forceinline__ unsigned short f2bf(float f) {
    __hip_bfloat16 h = __float2bfloat16(f);
    union { __hip_bfloat16 h; unsigned short s; } r;
    r.h = h;
    return r.s;
}
__device__ __forceinline__ float bf2f(unsigned short s) {
    union { unsigned short s; __hip_bfloat16 h; } r;
    r.s = s;
    return __bfloat162float(r.h);
}

// ---------------------------------------------------------------------------
// Split-bf16 MFMA GEMM: 128x128 tile, BK=32, 256 threads (4 waves, 2x2).
// C = Ahi*Bhi + Alo*Bhi + Ahi*Blo (fp32-grade accuracy).
// ---------------------------------------------------------------------------
#define GBM 128
#define GBN 128
#define GBK 32

__device__ __forceinline__ void cvt_hilo4(const float* x, ushort4& h, ushort4& l) {
    h.x = f2bf(x[0]); l.x = f2bf(x[0] - bf2f(h.x));
    h.y = f2bf(x[1]); l.y = f2bf(x[1] - bf2f(h.y));
    h.z = f2bf(x[2]); l.z = f2bf(x[2] - bf2f(h.z));
    h.w = f2bf(x[3]); l.w = f2bf(x[3] - bf2f(h.w));
}

// Fused QKV projection. Epilogue writes:
//   q  -> fp32 [B,H,S,HD]
//   k  -> bf16 hi/lo ushort pair [B,H,S,HD]  (for split-bf16 QK^T)
//   v  -> bf16 ushort [B,H,S,HD]
__global__ __launch_bounds__(256) void qkv_gemm(
    const float* __restrict__ X,
    const float* __restrict__ Wq, const float* __restrict__ bq,
    const float* __restrict__ Wk, const float* __restrict__ bk,
    const float* __restrict__ Wv, const float* __restrict__ bv,
    float* __restrict__ qo, unsigned short* __restrict__ khi,
    unsigned short* __restrict__ klo, unsigned short* __restrict__ vbf)
{
    __shared__ __align__(16) unsigned short Ah[8 * 512];
    __shared__ __align__(16) unsigned short Al[8 * 512];
    __shared__ __align__(16) unsigned short Bh[8 * 512];
    __shared__ __align__(16) unsigned short Bl[8 * 512];

    const int tid = threadIdx.x;
    const int m0 = blockIdx.y * GBM;
    const int n0 = blockIdx.x * GBN;
    const int lane = tid & 63;
    const int w = tid >> 6;
    const int wm = w & 1, wn = w >> 1;
    const int l15 = lane & 15, quad = lane >> 4;

    const int am0 = (tid >> 3) * 4;
    const int ak0 = (tid & 7) * 4;
    const float* Ap = X + (size_t)(m0 + am0) * DD + ak0;
    const int aLane = (am0 & 15) + 16 * (ak0 >> 3);
    const int aChunkBase = (am0 >> 4) * 512;
    const int aJ = ak0 & 7;

    const int bk0 = (tid >> 5) * 4;
    const int bn0 = (tid & 31) * 4;
    const int ng = n0 + bn0;
    const int sel = ng >> 10;
    const int hh  = (ng >> 6) & 15;
    const int ee  = ng & 63;
    const float* Wsel = (sel == 0) ? Wq : ((sel == 1) ? Wk : Wv);
    const float* Bp = Wsel + (size_t)hh * (DD * HD) + ee;

    f32x4 acc[4][4];
#pragma unroll
    for (int i = 0; i < 4; i++)
#pragma unroll
        for (int j = 0; j < 4; j++) acc[i][j] = (f32x4){0.f, 0.f, 0.f, 0.f};

    for (int kt = 0; kt < DD; kt += GBK) {
        float4 av[4], bv4[4];
#pragma unroll
        for (int r = 0; r < 4; r++)
            av[r] = *(const float4*)(Ap + (size_t)r * DD + kt);
#pragma unroll
        for (int r = 0; r < 4; r++)
            bv4[r] = *(const float4*)(Bp + (size_t)(kt + bk0 + r) * HD);

        __syncthreads();

#pragma unroll
        for (int r = 0; r < 4; r++) {
            ushort4 h, l;
            cvt_hilo4((const float*)&av[r], h, l);
            const int addr = aChunkBase + (aLane + r) * 8 + aJ;
            *(ushort4*)&Ah[addr] = h;
            *(ushort4*)&Al[addr] = l;
        }
#pragma unroll
        for (int c = 0; c < 4; c++) {
            float kv[4];
            kv[0] = ((const float*)&bv4[0])[c];
            kv[1] = ((const float*)&bv4[1])[c];
            kv[2] = ((const float*)&bv4[2])[c];
            kv[3] = ((const float*)&bv4[3])[c];
            ushort4 h, l;
            cvt_hilo4(kv, h, l);
            const int n = bn0 + c;
            const int addr = (n >> 4) * 512 + ((n & 15) + 16 * (bk0 >> 3)) * 8 + (bk0 & 7);
            *(ushort4*)&Bh[addr] = h;
            *(ushort4*)&Bl[addr] = l;
        }
        __syncthreads();

        bf16x8 ah[4], al[4];
#pragma unroll
        for (int ms = 0; ms < 4; ms++) {
            const int ca = (wm * 4 + ms) * 512 + lane * 8;
            ah[ms] = *(const bf16x8*)&Ah[ca];
            al[ms] = *(const bf16x8*)&Al[ca];
        }
#pragma unroll
        for (int ns = 0; ns < 4; ns++) {
            const int cb = (wn * 4 + ns) * 512 + lane * 8;
            bf16x8 bh = *(const bf16x8*)&Bh[cb];
            bf16x8 bl = *(const bf16x8*)&Bl[cb];
#pragma unroll
            for (int ms = 0; ms < 4; ms++) {
                acc[ms][ns] = __builtin_amdgcn_mfma_f32_16x16x32_bf16(ah[ms], bh, acc[ms][ns], 0, 0, 0);
                acc[ms][ns] = __builtin_amdgcn_mfma_f32_16x16x32_bf16(al[ms], bh, acc[ms][ns], 0, 0, 0);
                acc[ms][ns] = __builtin_amdgcn_mfma_f32_16x16x32_bf16(ah[ms], bl, acc[ms][ns], 0, 0, 0);
            }
        }
    }

    // epilogue: bias + scatter. sel is block-uniform (GBN=128 divides 1024).
#pragma unroll
    for (int ms = 0; ms < 4; ms++) {
#pragma unroll
        for (int rr = 0; rr < 4; rr++) {
            const int m = m0 + wm * 64 + ms * 16 + quad * 4 + rr;
            const int b = m >> 11;
            const int s = m & (SS - 1);
#pragma unroll
            for (int ns = 0; ns < 4; ns++) {
                const int n = n0 + wn * 64 + ns * 16 + l15;
                const int h = (n >> 6) & 15;
                const int e = n & 63;
                const size_t ofs = (((size_t)b * HH + h) * SS + s) * HD + e;
                if (sel == 0) {
                    qo[ofs] = acc[ms][ns][rr] + bq[h * HD + e];
                } else if (sel == 1) {
                    float val = acc[ms][ns][rr] + bk[h * HD + e];
                    unsigned short hb = f2bf(val);
                    khi[ofs] = hb;
                    klo[ofs] = f2bf(val - bf2f(hb));
                } else {
                    vbf[ofs] = f2bf(acc[ms][ns][rr] + bv[h * HD + e]);
                }
            }
        }
    }
}

// Output projection: out = ctx @ Wo + bo.
__global__ __launch_bounds__(256) void out_gemm(
    const float* __restrict__ Ctx, const float* __restrict__ Wo,
    const float* __restrict__ bo, float* __restrict__ out)
{
    __shared__ __align__(16) unsigned short Ah[8 * 512];
    __shared__ __align__(16) unsigned short Al[8 * 512];
    __shared__ __align__(16) unsigned short Bh[8 * 512];
    __shared__ __align__(16) unsigned short Bl[8 * 512];

    const int tid = threadIdx.x;
    const int m0 = blockIdx.y * GBM;
    const int n0 = blockIdx.x * GBN;
    const int lane = tid & 63;
    const int w = tid >> 6;
    const int wm = w & 1, wn = w >> 1;
    const int l15 = lane & 15, quad = lane >> 4;

    const int am0 = (tid >> 3) * 4;
    const int ak0 = (tid & 7) * 4;
    const float* Ap = Ctx + (size_t)(m0 + am0) * DD + ak0;
    const int aLane = (am0 & 15) + 16 * (ak0 >> 3);
    const int aChunkBase = (am0 >> 4) * 512;
    const int aJ = ak0 & 7;

    const int bk0 = (tid >> 5) * 4;
    const int bn0 = (tid & 31) * 4;
    const float* Bp = Wo + (size_t)(n0 + bn0);

    f32x4 acc[4][4];
#pragma unroll
    for (int i = 0; i < 4; i++)
#pragma unroll
        for (int j = 0; j < 4; j++) acc[i][j] = (f32x4){0.f, 0.f, 0.f, 0.f};

    for (int kt = 0; kt < DD; kt += GBK) {
        float4 av[4], bv4[4];
#pragma unroll
        for (int r = 0; r < 4; r++)
            av[r] = *(const float4*)(Ap + (size_t)r * DD + kt);
#pragma unroll
        for (int r = 0; r < 4; r++)
            bv4[r] = *(const float4*)(Bp + (size_t)(kt + bk0 + r) * DD);

        __syncthreads();

#pragma unroll
        for (int r = 0; r < 4; r++) {
            ushort4 h, l;
            cvt_hilo4((const float*)&av[r], h, l);
            const int addr = aChunkBase + (aLane + r) * 8 + aJ;
            *(ushort4*)&Ah[addr] = h;
            *(ushort4*)&Al[addr] = l;
        }
#pragma unroll
        for (int c = 0; c < 4; c++) {
            float kv[4];
            kv[0] = ((const float*)&bv4[0])[c];
            kv[1] = ((const float*)&bv4[1])[c];
            kv[2] = ((const float*)&bv4[2])[c];
            kv[3] = ((const float*)&bv4[3])[c];
            ushort4 h, l;
            cvt_hilo4(kv, h, l);
            const int n = bn0 + c;
            const int addr = (n >> 4) * 512 + ((n & 15) + 16 * (bk0 >> 3)) * 8 + (bk0 & 7);
            *(ushort4*)&Bh[addr] = h;
            *(ushort4*)&Bl[addr] = l;
        }
        __syncthreads();

        bf16x8 ah[4], al[4];
#pragma unroll
        for (int ms = 0; ms < 4; ms++) {
            const int ca = (wm * 4 + ms) * 512 + lane * 8;
            ah[ms] = *(const bf16x8*)&Ah[ca];
            al[ms] = *(const bf16x8*)&Al[ca];
        }
#pragma unroll
        for (int ns = 0; ns < 4; ns++) {
            const int cb = (wn * 4 + ns) * 512 + lane * 8;
            bf16x8 bh = *(const bf16x8*)&Bh[cb];
            bf16x8 bl = *(const bf16x8*)&Bl[cb];
#pragma unroll
            for (int ms = 0; ms < 4; ms++) {
                acc[ms][ns] = __builtin_amdgcn_mfma_f32_16x16x32_bf16(ah[ms], bh, acc[ms][ns], 0, 0, 0);
                acc[ms][ns] = __builtin_amdgcn_mfma_f32_16x16x32_bf16(al[ms], bh, acc[ms][ns], 0, 0, 0);
                acc[ms][ns] = __builtin_amdgcn_mfma_f32_16x16x32_bf16(ah[ms], bl, acc[ms][ns], 0, 0, 0);
            }
        }
    }

#pragma unroll
    for (int ms = 0; ms < 4; ms++) {
#pragma unroll
        for (int rr = 0; rr < 4; rr++) {
            const size_t m = (size_t)(m0 + wm * 64 + ms * 16 + quad * 4 + rr);
#pragma unroll
            for (int ns = 0; ns < 4; ns++) {
                const int n = n0 + wn * 64 + ns * 16 + l15;
                out[m * DD + n] = acc[ms][ns][rr] + bo[n];
            }
        }
    }
}

// ---------------------------------------------------------------------------
// kmax prepass: kc[bh] = max_key ||k|| * 1.01 * (0.125 * log2(e))
// ---------------------------------------------------------------------------
#define C1 0.1803368801111204f   // 0.125 * log2(e)

__global__ __launch_bounds__(256) void kmax_prep(
    const unsigned short* __restrict__ khi, float* __restrict__ kc)
{
    __shared__ float red[256];
    const int bh = blockIdx.x;
    const int tid = threadIdx.x;
    const unsigned short* base = khi + (size_t)bh * SS * HD;
    float mx = 0.0f;
    for (int key = tid; key < SS; key += 256) {
        const unsigned short* kr = base + (size_t)key * HD;
        float s = 0.0f;
#pragma unroll
        for (int j8 = 0; j8 < 8; j8++) {
            bf16x8 vv = *(const bf16x8*)&kr[j8 * 8];
#pragma unroll
            for (int j = 0; j < 8; j++) {
                float x = bf2f((unsigned short)vv[j]);
                s = fmaf(x, x, s);
            }
        }
        mx = fmaxf(mx, s);
    }
    red[tid] = mx;
    __syncthreads();
    for (int s2 = 128; s2 > 0; s2 >>= 1) {
        if (tid < s2) red[tid] = fmaxf(red[tid], red[tid + s2]);
        __syncthreads();
    }
    if (tid == 0) kc[bh] = sqrtf(red[0]) * 1.01f * C1;
}

// ---------------------------------------------------------------------------
// MFMA flash attention, fixed-m softmax (norm bound), pre-converted bf16 K/V.
// Block = 256 threads (4 waves); wave w owns 16 q rows. Q tile = 64 rows,
// K tile = 64 keys. p = exp2(qk*C1 - M2_row), M2_row = ||q_row||*kc[bh].
// l deferred to end-of-kernel reduction (fixed m => exact).
// ---------------------------------------------------------------------------
#define TQB 64
#define TKB 64
#define KSTR 72

__global__ __launch_bounds__(256, 4) void attn_mfma(
    const float* __restrict__ q, const unsigned short* __restrict__ khi,
    const unsigned short* __restrict__ klo, const unsigned short* __restrict__ vbf,
    const float* __restrict__ kc, float* __restrict__ ctx)
{
    __shared__ __align__(16) unsigned short KhiL[TKB * KSTR];
    __shared__ __align__(16) unsigned short KloL[TKB * KSTR];
    __shared__ __align__(16) unsigned short VtL [HD * KSTR];
    __shared__ __align__(16) unsigned short PsL [4][16 * KSTR];

    const int tid  = threadIdx.x;
    const int lane = tid & 63;
    const int w    = tid >> 6;
    const int l15  = lane & 15;
    const int quad = lane >> 4;
    const int bh   = blockIdx.y;
    const int q0   = blockIdx.x * TQB;

    // ---- Q A-frags (hi/lo) + row norm
    const float* qrow = q + ((size_t)bh * SS + q0 + w * 16 + l15) * HD;
    bf16x8 qhi[2], qlo[2];
    float nq2 = 0.0f;
#pragma unroll
    for (int dstep = 0; dstep < 2; dstep++) {
#pragma unroll
        for (int j = 0; j < 8; j++) {
            float x = qrow[dstep * 32 + quad * 8 + j];
            nq2 = fmaf(x, x, nq2);
            unsigned short h = f2bf(x);
            qhi[dstep][j] = (short)h;
            qlo[dstep][j] = (short)f2bf(x - bf2f(h));
        }
    }
    nq2 += __shfl_xor(nq2, 16);
    nq2 += __shfl_xor(nq2, 32);
    const float M2 = sqrtf(nq2) * kc[bh];
    float M2r[4];
#pragma unroll
    for (int rr = 0; rr < 4; rr++)
        M2r[rr] = __shfl(M2, quad * 4 + rr);   // row owner: lane (quad*4+rr), l15==row

    f32x4 o[4];
#pragma unroll
    for (int e = 0; e < 4; e++) o[e] = (f32x4){0.f, 0.f, 0.f, 0.f};
    float lpart[4] = {0.f, 0.f, 0.f, 0.f};

    const int rg = tid >> 4;      // V staging coords
    const int cg = tid & 15;
    const unsigned short* kb0 = khi + (size_t)bh * SS * HD;
    const unsigned short* lb0 = klo + (size_t)bh * SS * HD;
    const unsigned short* vb0 = vbf + (size_t)bh * SS * HD;

    for (int t = 0; t < SS / TKB; t++) {
        __syncthreads();

        // ---- stage K hi/lo: pure 16B copies (8 d-elems/lane)
        const unsigned short* kb = kb0 + (size_t)t * TKB * HD;
        const unsigned short* lb = lb0 + (size_t)t * TKB * HD;
#pragma unroll
        for (int p = 0; p < 2; p++) {
            int idx = tid + p * 256;
            int key = idx >> 3;
            int d8 = (idx & 7) * 8;
            *(bf16x8*)&KhiL[key * KSTR + d8] = *(const bf16x8*)&kb[key * HD + d8];
            *(bf16x8*)&KloL[key * KSTR + d8] = *(const bf16x8*)&lb[key * HD + d8];
        }
        // ---- stage V transposed: 4x4 u16 register repack
        const unsigned short* vb = vb0 + (size_t)t * TKB * HD;
        u16x4 r0 = *(const u16x4*)&vb[(rg * 4 + 0) * HD + cg * 4];
        u16x4 r1 = *(const u16x4*)&vb[(rg * 4 + 1) * HD + cg * 4];
        u16x4 r2 = *(const u16x4*)&vb[(rg * 4 + 2) * HD + cg * 4];
        u16x4 r3 = *(const u16x4*)&vb[(rg * 4 + 3) * HD + cg * 4];
#pragma unroll
        for (int c = 0; c < 4; c++) {
            u16x4 tv = (u16x4){r0[c], r1[c], r2[c], r3[c]};
            *(u16x4*)&VtL[(cg * 4 + c) * KSTR + rg * 4] = tv;
        }
        __syncthreads();

        // ---- scores: 4 ksub x (3-MFMA split x 2 dstep)
        f32x4 sc[4];
#pragma unroll
        for (int ksub = 0; ksub < 4; ksub++) {
            const int krow = (ksub * 16 + l15) * KSTR + quad * 8;
            bf16x8 kh0 = *(const bf16x8*)&KhiL[krow];
            bf16x8 kh1 = *(const bf16x8*)&KhiL[krow + 32];
            bf16x8 kl0 = *(const bf16x8*)&KloL[krow];
            bf16x8 kl1 = *(const bf16x8*)&KloL[krow + 32];
            f32x4 acc = (f32x4){0.f, 0.f, 0.f, 0.f};
            acc = __builtin_amdgcn_mfma_f32_16x16x32_bf16(qhi[0], kh0, acc, 0, 0, 0);
            acc = __builtin_amdgcn_mfma_f32_16x16x32_bf16(qlo[0], kh0, acc, 0, 0, 0);
            acc = __builtin_amdgcn_mfma_f32_16x16x32_bf16(qhi[0], kl0, acc, 0, 0, 0);
            acc = __builtin_amdgcn_mfma_f32_16x16x32_bf16(qhi[1], kh1, acc, 0, 0, 0);
            acc = __builtin_amdgcn_mfma_f32_16x16x32_bf16(qlo[1], kh1, acc, 0, 0, 0);
            acc = __builtin_amdgcn_mfma_f32_16x16x32_bf16(qhi[1], kl1, acc, 0, 0, 0);
            sc[ksub] = acc;
        }

        // ---- fixed-m softmax: p = exp2(qk*C1 - M2_row); defer l reduction
#pragma unroll
        for (int rr = 0; rr < 4; rr++) {
            const int prow = (quad * 4 + rr) * KSTR;
#pragma unroll
            for (int ksub = 0; ksub < 4; ksub++) {
                float p = exp2f(fmaf(sc[ksub][rr], C1, -M2r[rr]));
                unsigned short pb = f2bf(p);
                lpart[rr] += bf2f(pb);
                PsL[w][prow + ksub * 16 + l15] = pb;
            }
        }

        // ---- PV: o += P(16x64) x V(64x64)   (PsL wave-private)
#pragma unroll
        for (int kj = 0; kj < 2; kj++) {
            bf16x8 pa = *(const bf16x8*)&PsL[w][l15 * KSTR + kj * 32 + quad * 8];
#pragma unroll
            for (int esub = 0; esub < 4; esub++) {
                bf16x8 vbr = *(const bf16x8*)&VtL[(esub * 16 + l15) * KSTR + kj * 32 + quad * 8];
                o[esub] = __builtin_amdgcn_mfma_f32_16x16x32_bf16(pa, vbr, o[esub], 0, 0, 0);
            }
        }
    }

    // ---- l reduction (over 16 col-lanes) + epilogue
    float linv[4];
#pragma unroll
    for (int rr = 0; rr < 4; rr++) {
        float l = lpart[rr];
        l += __shfl_xor(l, 1);
        l += __shfl_xor(l, 2);
        l += __shfl_xor(l, 4);
        l += __shfl_xor(l, 8);
        linv[rr] = 1.0f / l;
    }
    const int b = bh >> 4;
    const int h = bh & 15;
#pragma unroll
    for (int rr = 0; rr < 4; rr++) {
        const int row = q0 + w * 16 + quad * 4 + rr;
#pragma unroll
        for (int esub = 0; esub < 4; esub++) {
            ctx[((size_t)b * SS + row) * DD + h * HD + esub * 16 + l15] =
                o[esub][rr] * linv[rr];
        }
    }
}

// ---------------------------------------------------------------------------
extern "C" void kernel_launch(void* const* d_in, const int* in_sizes, int n_in,
                              void* d_out, int out_size, void* d_ws, size_t ws_size,
                              hipStream_t stream) {
    const float* X  = (const float*)d_in[0];
    const float* Wq = (const float*)d_in[1];
    const float* bq = (const float*)d_in[2];
    const float* Wk = (const float*)d_in[3];
    const float* bk = (const float*)d_in[4];
    const float* Wv = (const float*)d_in[5];
    const float* bv = (const float*)d_in[6];
    const float* Wo = (const float*)d_in[7];
    const float* bo = (const float*)d_in[8];
    float* out = (float*)d_out;

    // ws layout (NEL = 4.19M elems; NB = 16.78 MB):
    //   [0, NB)          q fp32
    //   [NB, 2NB)        ctx fp32
    //   [2NB, 2.5NB)     khi u16
    //   [2.5NB, 3NB)     klo u16
    //   [3NB, 3.5NB)     vbf u16
    //   [3.5NB, +128B)   kc f32[32]
    // total ~58.7 MB (< 67 MB known-good)
    const size_t NEL = (size_t)BB * HH * SS * HD;
    const size_t NB = 4ull * NEL;
    unsigned char* w8 = (unsigned char*)d_ws;
    float* qws          = (float*)(w8);
    float* cws          = (float*)(w8 + NB);
    unsigned short* khi = (unsigned short*)(w8 + 2 * NB);
    unsigned short* klo = (unsigned short*)(w8 + 2 * NB + NB / 2);
    unsigned short* vbf = (unsigned short*)(w8 + 3 * NB);
    float* kc           = (float*)(w8 + 3 * NB + NB / 2);

    // 1) fused QKV projection (split-bf16 MFMA), writes q f32 + k hi/lo + v bf16
    qkv_gemm<<<dim3(3072 / GBN, 4096 / GBM), 256, 0, stream>>>(
        X, Wq, bq, Wk, bk, Wv, bv, qws, khi, klo, vbf);

    // 2) per-(b,h) key-norm bound
    kmax_prep<<<dim3(BB * HH), 256, 0, stream>>>(khi, kc);

    // 3) MFMA flash attention (fixed-m softmax)
    attn_mfma<<<dim3(SS / TQB, BB * HH), 256, 0, stream>>>(qws, khi, klo, vbf, kc, cws);

    // 4) output projection (split-bf16 MFMA)
    out_gemm<<<dim3(1024 / GBN, 4096 / GBM), 256, 0, stream>>>(cws, Wo, bo, out);
}

// Round 5
// 373.790 us; speedup vs baseline: 4.0186x; 1.0539x over previous
//
#include <hip/hip_runtime.h>
#include <hip/hip_bf16.h>
#include <math.h>

// Problem constants
#define BB 2
#define SS 2048
#define DD 1024
#define HH 16
#define HD 64

typedef __attribute__((ext_vector_type(8))) short bf16x8;
typedef __attribute__((ext_vector_type(4))) float f32x4;
typedef __attribute__((ext_vector_type(4))) unsigned short u16x4;

__device__ __forceinline__ unsigned short f2bf(float f) {
    __hip_bfloat16 h = __float2bfloat16(f);
    union { __hip_bfloat16 h; unsigned short s; } r;
    r.h = h;
    return r.s;
}
__device__ __forceinline__ float bf2f(unsigned short s) {
    union { unsigned short s; __hip_bfloat16 h; } r;
    r.s = s;
    return __bfloat162float(r.h);
}
__device__ __forceinline__ void cvt_hilo4(const float* x, ushort4& h, ushort4& l) {
    h.x = f2bf(x[0]); l.x = f2bf(x[0] - bf2f(h.x));
    h.y = f2bf(x[1]); l.y = f2bf(x[1] - bf2f(h.y));
    h.z = f2bf(x[2]); l.z = f2bf(x[2] - bf2f(h.z));
    h.w = f2bf(x[3]); l.w = f2bf(x[3] - bf2f(h.w));
}

// ---------------------------------------------------------------------------
// Split-bf16 MFMA GEMM: 128x128 tile, BK=32, 256 threads (4 waves, 2x2).
// C = Ahi*Bhi + Alo*Bhi + Ahi*Blo.
// LDS chunk layout (per 16-row/col group): elem (r16,k) at slot (k>>3)*16+r16,
// 8 u16 payload; frag read = ds_read_b128 at chunk*1024B + lane*16B (min-cycle).
// Staging assignments chosen so WRITES are also min-cycle (see session notes):
//   A: row = tid>>1, k = c*8 + (tid&1)*4  -> ushort4 writes, 4 accesses/bank
//   B: col = tid&127, k = (tid>>7)*16+kk  -> bf16x8 writes, 8 accesses/bank
// ---------------------------------------------------------------------------
#define GBM 128
#define GBN 128
#define GBK 32

// Fused QKV projection. Writes q fp32, k as bf16 hi/lo, v bf16, and
// atomicMax per-(b,h) max ||k||^2 into kc2 (float bits as uint; kc2 pre-zeroed).
__global__ __launch_bounds__(256) void qkv_gemm(
    const float* __restrict__ X,
    const float* __restrict__ Wq, const float* __restrict__ bq,
    const float* __restrict__ Wk, const float* __restrict__ bk,
    const float* __restrict__ Wv, const float* __restrict__ bv,
    float* __restrict__ qo, unsigned short* __restrict__ khi,
    unsigned short* __restrict__ klo, unsigned short* __restrict__ vbf,
    unsigned int* __restrict__ kc2)
{
    __shared__ __align__(16) unsigned short Ah[8 * 512];
    __shared__ __align__(16) unsigned short Al[8 * 512];
    __shared__ __align__(16) unsigned short Bh[8 * 512];
    __shared__ __align__(16) unsigned short Bl[8 * 512];

    const int tid = threadIdx.x;
    const int m0 = blockIdx.y * GBM;
    const int n0 = blockIdx.x * GBN;
    const int lane = tid & 63;
    const int w = tid >> 6;
    const int wm = w & 1, wn = w >> 1;
    const int l15 = lane & 15, quad = lane >> 4;

    // A staging: row = tid>>1, k-quads c*8 + (tid&1)*4
    const int arow = tid >> 1;
    const int akq  = tid & 1;
    const float* ApR = X + (size_t)(m0 + arow) * DD;
    const int aBase = (arow >> 4) * 512 + (arow & 15) * 8 + akq * 4;  // + c*128

    // B staging: col = tid&127, k-half = tid>>7
    const int bn  = tid & 127;
    const int bkh = tid >> 7;
    const int ngg = n0 + bn;
    const int sel = ngg >> 10;                 // block-uniform
    const int bhh = (ngg >> 6) & 15;
    const int bee = ngg & 63;
    const float* Wsel = (sel == 0) ? Wq : ((sel == 1) ? Wk : Wv);
    const float* Bp = Wsel + (size_t)bhh * (DD * HD) + bee;   // + k*HD
    const int bBase = (bn >> 4) * 512 + (bn & 15) * 8;        // + (bkh*2+j2)*128

    f32x4 acc[4][4];
#pragma unroll
    for (int i = 0; i < 4; i++)
#pragma unroll
        for (int j = 0; j < 4; j++) acc[i][j] = (f32x4){0.f, 0.f, 0.f, 0.f};

    for (int kt = 0; kt < DD; kt += GBK) {
        float4 av[4];
#pragma unroll
        for (int c = 0; c < 4; c++)
            av[c] = *(const float4*)(ApR + kt + c * 8 + akq * 4);
        float wv[16];
#pragma unroll
        for (int kk = 0; kk < 16; kk++)
            wv[kk] = Bp[(size_t)(kt + bkh * 16 + kk) * HD];

        __syncthreads();   // prior compute done before overwrite

#pragma unroll
        for (int c = 0; c < 4; c++) {
            ushort4 h, l;
            cvt_hilo4((const float*)&av[c], h, l);
            *(ushort4*)&Ah[aBase + c * 128] = h;
            *(ushort4*)&Al[aBase + c * 128] = l;
        }
#pragma unroll
        for (int j2 = 0; j2 < 2; j2++) {
            bf16x8 vh, vl;
#pragma unroll
            for (int j = 0; j < 8; j++) {
                float x = wv[j2 * 8 + j];
                unsigned short hb = f2bf(x);
                vh[j] = (short)hb;
                vl[j] = (short)f2bf(x - bf2f(hb));
            }
            const int addr = bBase + (bkh * 2 + j2) * 128;
            *(bf16x8*)&Bh[addr] = vh;
            *(bf16x8*)&Bl[addr] = vl;
        }
        __syncthreads();

        bf16x8 ah[4], al[4];
#pragma unroll
        for (int ms = 0; ms < 4; ms++) {
            const int ca = (wm * 4 + ms) * 512 + lane * 8;
            ah[ms] = *(const bf16x8*)&Ah[ca];
            al[ms] = *(const bf16x8*)&Al[ca];
        }
#pragma unroll
        for (int ns = 0; ns < 4; ns++) {
            const int cb = (wn * 4 + ns) * 512 + lane * 8;
            bf16x8 bh = *(const bf16x8*)&Bh[cb];
            bf16x8 bl = *(const bf16x8*)&Bl[cb];
#pragma unroll
            for (int ms = 0; ms < 4; ms++) {
                acc[ms][ns] = __builtin_amdgcn_mfma_f32_16x16x32_bf16(ah[ms], bh, acc[ms][ns], 0, 0, 0);
                acc[ms][ns] = __builtin_amdgcn_mfma_f32_16x16x32_bf16(al[ms], bh, acc[ms][ns], 0, 0, 0);
                acc[ms][ns] = __builtin_amdgcn_mfma_f32_16x16x32_bf16(ah[ms], bl, acc[ms][ns], 0, 0, 0);
            }
        }
    }

    // epilogue: bias + scatter; for k also track max row-||k||^2 per wave.
    const int hw = ((n0 + wn * 64) >> 6) & 15;   // wave-uniform head
    const int bblk = m0 >> 11;                   // block-uniform batch
    float wmx = 0.0f;
#pragma unroll
    for (int ms = 0; ms < 4; ms++) {
#pragma unroll
        for (int rr = 0; rr < 4; rr++) {
            const int m = m0 + wm * 64 + ms * 16 + quad * 4 + rr;
            const int s = m & (SS - 1);
            float v2 = 0.0f;
#pragma unroll
            for (int ns = 0; ns < 4; ns++) {
                const int e = ns * 16 + l15;
                const size_t ofs = (((size_t)bblk * HH + hw) * SS + s) * HD + e;
                if (sel == 0) {
                    qo[ofs] = acc[ms][ns][rr] + bq[hw * HD + e];
                } else if (sel == 1) {
                    float val = acc[ms][ns][rr] + bk[hw * HD + e];
                    unsigned short hb = f2bf(val);
                    khi[ofs] = hb;
                    klo[ofs] = f2bf(val - bf2f(hb));
                    v2 = fmaf(val, val, v2);
                } else {
                    vbf[ofs] = f2bf(acc[ms][ns][rr] + bv[hw * HD + e]);
                }
            }
            if (sel == 1) {
                v2 += __shfl_xor(v2, 1);
                v2 += __shfl_xor(v2, 2);
                v2 += __shfl_xor(v2, 4);
                v2 += __shfl_xor(v2, 8);
                wmx = fmaxf(wmx, v2);
            }
        }
    }
    if (sel == 1) {
        wmx = fmaxf(wmx, __shfl_xor(wmx, 16));
        wmx = fmaxf(wmx, __shfl_xor(wmx, 32));
        if (lane == 0)
            atomicMax(&kc2[bblk * HH + hw], __float_as_uint(wmx));
    }
}

// Output projection: out = ctx @ Wo + bo.
__global__ __launch_bounds__(256) void out_gemm(
    const float* __restrict__ Ctx, const float* __restrict__ Wo,
    const float* __restrict__ bo, float* __restrict__ out)
{
    __shared__ __align__(16) unsigned short Ah[8 * 512];
    __shared__ __align__(16) unsigned short Al[8 * 512];
    __shared__ __align__(16) unsigned short Bh[8 * 512];
    __shared__ __align__(16) unsigned short Bl[8 * 512];

    const int tid = threadIdx.x;
    const int m0 = blockIdx.y * GBM;
    const int n0 = blockIdx.x * GBN;
    const int lane = tid & 63;
    const int w = tid >> 6;
    const int wm = w & 1, wn = w >> 1;
    const int l15 = lane & 15, quad = lane >> 4;

    const int arow = tid >> 1;
    const int akq  = tid & 1;
    const float* ApR = Ctx + (size_t)(m0 + arow) * DD;
    const int aBase = (arow >> 4) * 512 + (arow & 15) * 8 + akq * 4;

    const int bn  = tid & 127;
    const int bkh = tid >> 7;
    const float* Bp = Wo + (size_t)(n0 + bn);
    const int bBase = (bn >> 4) * 512 + (bn & 15) * 8;

    f32x4 acc[4][4];
#pragma unroll
    for (int i = 0; i < 4; i++)
#pragma unroll
        for (int j = 0; j < 4; j++) acc[i][j] = (f32x4){0.f, 0.f, 0.f, 0.f};

    for (int kt = 0; kt < DD; kt += GBK) {
        float4 av[4];
#pragma unroll
        for (int c = 0; c < 4; c++)
            av[c] = *(const float4*)(ApR + kt + c * 8 + akq * 4);
        float wv[16];
#pragma unroll
        for (int kk = 0; kk < 16; kk++)
            wv[kk] = Bp[(size_t)(kt + bkh * 16 + kk) * DD];

        __syncthreads();

#pragma unroll
        for (int c = 0; c < 4; c++) {
            ushort4 h, l;
            cvt_hilo4((const float*)&av[c], h, l);
            *(ushort4*)&Ah[aBase + c * 128] = h;
            *(ushort4*)&Al[aBase + c * 128] = l;
        }
#pragma unroll
        for (int j2 = 0; j2 < 2; j2++) {
            bf16x8 vh, vl;
#pragma unroll
            for (int j = 0; j < 8; j++) {
                float x = wv[j2 * 8 + j];
                unsigned short hb = f2bf(x);
                vh[j] = (short)hb;
                vl[j] = (short)f2bf(x - bf2f(hb));
            }
            const int addr = bBase + (bkh * 2 + j2) * 128;
            *(bf16x8*)&Bh[addr] = vh;
            *(bf16x8*)&Bl[addr] = vl;
        }
        __syncthreads();

        bf16x8 ah[4], al[4];
#pragma unroll
        for (int ms = 0; ms < 4; ms++) {
            const int ca = (wm * 4 + ms) * 512 + lane * 8;
            ah[ms] = *(const bf16x8*)&Ah[ca];
            al[ms] = *(const bf16x8*)&Al[ca];
        }
#pragma unroll
        for (int ns = 0; ns < 4; ns++) {
            const int cb = (wn * 4 + ns) * 512 + lane * 8;
            bf16x8 bh = *(const bf16x8*)&Bh[cb];
            bf16x8 bl = *(const bf16x8*)&Bl[cb];
#pragma unroll
            for (int ms = 0; ms < 4; ms++) {
                acc[ms][ns] = __builtin_amdgcn_mfma_f32_16x16x32_bf16(ah[ms], bh, acc[ms][ns], 0, 0, 0);
                acc[ms][ns] = __builtin_amdgcn_mfma_f32_16x16x32_bf16(al[ms], bh, acc[ms][ns], 0, 0, 0);
                acc[ms][ns] = __builtin_amdgcn_mfma_f32_16x16x32_bf16(ah[ms], bl, acc[ms][ns], 0, 0, 0);
            }
        }
    }

#pragma unroll
    for (int ms = 0; ms < 4; ms++) {
#pragma unroll
        for (int rr = 0; rr < 4; rr++) {
            const size_t m = (size_t)(m0 + wm * 64 + ms * 16 + quad * 4 + rr);
#pragma unroll
            for (int ns = 0; ns < 4; ns++) {
                const int n = n0 + wn * 64 + ns * 16 + l15;
                out[m * DD + n] = acc[ms][ns][rr] + bo[n];
            }
        }
    }
}

// ---------------------------------------------------------------------------
// MFMA flash attention, fixed-m softmax, XOR-swizzled LDS (conflict-free).
// Block = 256 threads (4 waves); wave w owns 32 q rows (2 m-subtiles).
// Tile layout: off(row,col) = row*64 + ((col>>3 ^ (row&7))<<3) + (col&7).
// ---------------------------------------------------------------------------
#define TQB 128
#define TKB 64
#define C1 0.1803368801111204f   // 0.125 * log2(e)

__device__ __forceinline__ int swz(int row, int grp) {
    return (row << 6) + (((grp) ^ (row & 7)) << 3);
}

__global__ __launch_bounds__(256) void attn_mfma(
    const float* __restrict__ q, const unsigned short* __restrict__ khi,
    const unsigned short* __restrict__ klo, const unsigned short* __restrict__ vbf,
    const unsigned int* __restrict__ kc2, float* __restrict__ ctx)
{
    __shared__ __align__(16) unsigned short KhiL[TKB * 64];
    __shared__ __align__(16) unsigned short KloL[TKB * 64];
    __shared__ __align__(16) unsigned short VtL [HD * 64];
    __shared__ __align__(16) unsigned short PsL [4][32 * 64];

    const int tid  = threadIdx.x;
    const int lane = tid & 63;
    const int w    = tid >> 6;
    const int l15  = lane & 15;
    const int quad = lane >> 4;
    const int bh   = blockIdx.y;
    const int q0   = blockIdx.x * TQB;

    const float kfac = sqrtf(__uint_as_float(kc2[bh])) * 1.01f * C1;

    // ---- Q A-frags (hi/lo) + per-row norm -> fixed-m bound
    bf16x8 qhi[2][2], qlo[2][2];
    float M2r[2][4];
#pragma unroll
    for (int msub = 0; msub < 2; msub++) {
        const float* qrow = q + ((size_t)bh * SS + q0 + w * 32 + msub * 16 + l15) * HD;
        float nq2 = 0.0f;
#pragma unroll
        for (int dstep = 0; dstep < 2; dstep++) {
            float4 a = *(const float4*)(qrow + dstep * 32 + quad * 8);
            float4 b = *(const float4*)(qrow + dstep * 32 + quad * 8 + 4);
            float xs[8] = {a.x, a.y, a.z, a.w, b.x, b.y, b.z, b.w};
#pragma unroll
            for (int j = 0; j < 8; j++) {
                float x = xs[j];
                nq2 = fmaf(x, x, nq2);
                unsigned short h = f2bf(x);
                qhi[msub][dstep][j] = (short)h;
                qlo[msub][dstep][j] = (short)f2bf(x - bf2f(h));
            }
        }
        nq2 += __shfl_xor(nq2, 16);
        nq2 += __shfl_xor(nq2, 32);
        const float M2 = sqrtf(nq2) * kfac;
#pragma unroll
        for (int rr = 0; rr < 4; rr++)
            M2r[msub][rr] = __shfl(M2, quad * 4 + rr);
    }

    f32x4 o[2][4];
    float lpart[2][4];
#pragma unroll
    for (int ms = 0; ms < 2; ms++)
#pragma unroll
        for (int e = 0; e < 4; e++) o[ms][e] = (f32x4){0.f, 0.f, 0.f, 0.f};
#pragma unroll
    for (int ms = 0; ms < 2; ms++)
#pragma unroll
        for (int rr = 0; rr < 4; rr++) lpart[ms][rr] = 0.0f;

    const int rg = tid >> 4;      // V staging: keys rg*4..+3
    const int cg = tid & 15;      //            e    cg*4..+3
    const unsigned short* kb0 = khi + (size_t)bh * SS * HD;
    const unsigned short* lb0 = klo + (size_t)bh * SS * HD;
    const unsigned short* vb0 = vbf + (size_t)bh * SS * HD;

    for (int t = 0; t < SS / TKB; t++) {
        __syncthreads();   // prior tile reads done

        // ---- stage K hi/lo (swizzled; min-cycle writes)
        const unsigned short* kb = kb0 + (size_t)t * TKB * HD;
        const unsigned short* lb = lb0 + (size_t)t * TKB * HD;
#pragma unroll
        for (int p = 0; p < 2; p++) {
            const int idx = tid + p * 256;
            const int key = idx >> 3;
            const int g = idx & 7;
            const int dst = swz(key, g);
            *(bf16x8*)&KhiL[dst] = *(const bf16x8*)&kb[key * HD + g * 8];
            *(bf16x8*)&KloL[dst] = *(const bf16x8*)&lb[key * HD + g * 8];
        }
        // ---- stage V transposed (4x4 u16 repack)
        const unsigned short* vb = vb0 + (size_t)t * TKB * HD;
        u16x4 r0 = *(const u16x4*)&vb[(rg * 4 + 0) * HD + cg * 4];
        u16x4 r1 = *(const u16x4*)&vb[(rg * 4 + 1) * HD + cg * 4];
        u16x4 r2 = *(const u16x4*)&vb[(rg * 4 + 2) * HD + cg * 4];
        u16x4 r3 = *(const u16x4*)&vb[(rg * 4 + 3) * HD + cg * 4];
#pragma unroll
        for (int c = 0; c < 4; c++) {
            u16x4 tv = (u16x4){r0[c], r1[c], r2[c], r3[c]};
            *(u16x4*)&VtL[swz(cg * 4 + c, rg >> 1) + (rg & 1) * 4] = tv;
        }
        __syncthreads();

        // ---- scores
        f32x4 sc[2][4];
#pragma unroll
        for (int ksub = 0; ksub < 4; ksub++) {
            const int row = ksub * 16 + l15;
            bf16x8 kh0 = *(const bf16x8*)&KhiL[swz(row, quad)];
            bf16x8 kh1 = *(const bf16x8*)&KhiL[swz(row, 4 + quad)];
            bf16x8 kl0 = *(const bf16x8*)&KloL[swz(row, quad)];
            bf16x8 kl1 = *(const bf16x8*)&KloL[swz(row, 4 + quad)];
#pragma unroll
            for (int msub = 0; msub < 2; msub++) {
                f32x4 a = (f32x4){0.f, 0.f, 0.f, 0.f};
                a = __builtin_amdgcn_mfma_f32_16x16x32_bf16(qhi[msub][0], kh0, a, 0, 0, 0);
                a = __builtin_amdgcn_mfma_f32_16x16x32_bf16(qlo[msub][0], kh0, a, 0, 0, 0);
                a = __builtin_amdgcn_mfma_f32_16x16x32_bf16(qhi[msub][0], kl0, a, 0, 0, 0);
                a = __builtin_amdgcn_mfma_f32_16x16x32_bf16(qhi[msub][1], kh1, a, 0, 0, 0);
                a = __builtin_amdgcn_mfma_f32_16x16x32_bf16(qlo[msub][1], kh1, a, 0, 0, 0);
                a = __builtin_amdgcn_mfma_f32_16x16x32_bf16(qhi[msub][1], kl1, a, 0, 0, 0);
                sc[msub][ksub] = a;
            }
        }

        // ---- fixed-m softmax; P to wave-private swizzled LDS
#pragma unroll
        for (int msub = 0; msub < 2; msub++) {
#pragma unroll
            for (int rr = 0; rr < 4; rr++) {
                const int prow = msub * 16 + quad * 4 + rr;
#pragma unroll
                for (int ksub = 0; ksub < 4; ksub++) {
                    float p = exp2f(fmaf(sc[msub][ksub][rr], C1, -M2r[msub][rr]));
                    unsigned short pb = f2bf(p);
                    lpart[msub][rr] += bf2f(pb);
                    PsL[w][swz(prow, ksub * 2 + (l15 >> 3)) + (l15 & 7)] = pb;
                }
            }
        }

        // ---- PV
#pragma unroll
        for (int kj = 0; kj < 2; kj++) {
            bf16x8 pa[2];
#pragma unroll
            for (int msub = 0; msub < 2; msub++)
                pa[msub] = *(const bf16x8*)&PsL[w][swz(msub * 16 + l15, kj * 4 + quad)];
#pragma unroll
            for (int esub = 0; esub < 4; esub++) {
                bf16x8 vr = *(const bf16x8*)&VtL[swz(esub * 16 + l15, kj * 4 + quad)];
                o[0][esub] = __builtin_amdgcn_mfma_f32_16x16x32_bf16(pa[0], vr, o[0][esub], 0, 0, 0);
                o[1][esub] = __builtin_amdgcn_mfma_f32_16x16x32_bf16(pa[1], vr, o[1][esub], 0, 0, 0);
            }
        }
    }

    // ---- deferred l + epilogue
    const int b = bh >> 4;
    const int h = bh & 15;
#pragma unroll
    for (int msub = 0; msub < 2; msub++) {
#pragma unroll
        for (int rr = 0; rr < 4; rr++) {
            float l = lpart[msub][rr];
            l += __shfl_xor(l, 1);
            l += __shfl_xor(l, 2);
            l += __shfl_xor(l, 4);
            l += __shfl_xor(l, 8);
            const float linv = 1.0f / l;
            const int row = q0 + w * 32 + msub * 16 + quad * 4 + rr;
#pragma unroll
            for (int esub = 0; esub < 4; esub++) {
                ctx[((size_t)b * SS + row) * DD + h * HD + esub * 16 + l15] =
                    o[msub][esub][rr] * linv;
            }
        }
    }
}

// ---------------------------------------------------------------------------
extern "C" void kernel_launch(void* const* d_in, const int* in_sizes, int n_in,
                              void* d_out, int out_size, void* d_ws, size_t ws_size,
                              hipStream_t stream) {
    const float* X  = (const float*)d_in[0];
    const float* Wq = (const float*)d_in[1];
    const float* bq = (const float*)d_in[2];
    const float* Wk = (const float*)d_in[3];
    const float* bk = (const float*)d_in[4];
    const float* Wv = (const float*)d_in[5];
    const float* bv = (const float*)d_in[6];
    const float* Wo = (const float*)d_in[7];
    const float* bo = (const float*)d_in[8];
    float* out = (float*)d_out;

    // ws layout: q f32 | ctx f32 | khi u16 | klo u16 | vbf u16 | kc2 u32[32]
    const size_t NEL = (size_t)BB * HH * SS * HD;   // 4194304
    const size_t NB = 4ull * NEL;
    unsigned char* w8 = (unsigned char*)d_ws;
    float* qws          = (float*)(w8);
    float* cws          = (float*)(w8 + NB);
    unsigned short* khi = (unsigned short*)(w8 + 2 * NB);
    unsigned short* klo = (unsigned short*)(w8 + 2 * NB + NB / 2);
    unsigned short* vbf = (unsigned short*)(w8 + 3 * NB);
    unsigned int* kc2   = (unsigned int*)(w8 + 3 * NB + NB / 2);

    hipMemsetAsync(kc2, 0, BB * HH * sizeof(unsigned int), stream);

    // 1) fused QKV projection
    qkv_gemm<<<dim3(3072 / GBN, 4096 / GBM), 256, 0, stream>>>(
        X, Wq, bq, Wk, bk, Wv, bv, qws, khi, klo, vbf, kc2);

    // 2) MFMA flash attention (fixed-m softmax, swizzled LDS)
    attn_mfma<<<dim3(SS / TQB, BB * HH), 256, 0, stream>>>(qws, khi, klo, vbf, kc2, cws);

    // 3) output projection
    out_gemm<<<dim3(1024 / GBN, 4096 / GBM), 256, 0, stream>>>(cws, Wo, bo, out);
}

// Round 6
// 271.045 us; speedup vs baseline: 5.5420x; 1.3791x over previous
//
#include <hip/hip_runtime.h>
#include <hip/hip_bf16.h>
#include <math.h>

// Problem constants
#define BB 2
#define SS 2048
#define DD 1024
#define HH 16
#define HD 64

typedef __attribute__((ext_vector_type(8))) _Float16 f16x8;
typedef __attribute__((ext_vector_type(8))) unsigned short u16x8;
typedef __attribute__((ext_vector_type(4))) float f32x4;
typedef __attribute__((ext_vector_type(4))) unsigned short u16x4;

__device__ __forceinline__ unsigned short hbits(_Float16 h) {
    union { _Float16 h; unsigned short s; } u; u.h = h; return u.s;
}

// ---------------------------------------------------------------------------
// Prepass: convert X -> fp16 (same layout) and W -> fp16 TRANSPOSED rows:
//   WTall[n][k], n in [0,3072) = (sel,h,e) qkv cols, n in [3072,4096) = Wo cols.
// Blocks 0..2047: X elementwise. Blocks 2048..3071: 64x64 transpose tiles.
// ---------------------------------------------------------------------------
__global__ __launch_bounds__(256) void prep_convert(
    const float* __restrict__ X,
    const float* __restrict__ Wq, const float* __restrict__ Wk,
    const float* __restrict__ Wv, const float* __restrict__ Wo,
    unsigned short* __restrict__ Xh, unsigned short* __restrict__ WT)
{
    __shared__ __align__(16) unsigned short LT[64 * 68];
    const int bid = blockIdx.x;
    const int tid = threadIdx.x;

    if (bid < 2048) {
        const int base = bid * 2048 + tid * 8;
        float4 a = *(const float4*)&X[base];
        float4 b = *(const float4*)&X[base + 4];
        u16x8 o;
        o[0] = hbits((_Float16)a.x); o[1] = hbits((_Float16)a.y);
        o[2] = hbits((_Float16)a.z); o[3] = hbits((_Float16)a.w);
        o[4] = hbits((_Float16)b.x); o[5] = hbits((_Float16)b.y);
        o[6] = hbits((_Float16)b.z); o[7] = hbits((_Float16)b.w);
        *(u16x8*)&Xh[base] = o;
        return;
    }

    const int t = bid - 2048;
    const float* src;
    size_t stride;
    int outRow0, kcol0;
    if (t < 768) {                       // qkv weights: W[h][d][e], stride_d = 64
        const int nt = t >> 4, ktile = t & 15;
        const int sel = nt >> 4, hh = nt & 15;
        const float* Ws = (sel == 0) ? Wq : ((sel == 1) ? Wk : Wv);
        src = Ws + (size_t)hh * (DD * HD) + (size_t)ktile * 64 * HD;
        stride = HD;
        outRow0 = nt * 64;
        kcol0 = ktile * 64;
    } else {                             // Wo[d][n], stride_d = 1024
        const int tt = t - 768;
        const int nt = tt & 15, ktile = tt >> 4;
        src = Wo + (size_t)ktile * 64 * DD + nt * 64;
        stride = DD;
        outRow0 = 3072 + nt * 64;
        kcol0 = ktile * 64;
    }

    const int e = tid & 63, dq = tid >> 6;
#pragma unroll
    for (int p = 0; p < 16; p++) {
        const int dl = p * 4 + dq;
        LT[e * 68 + dl] = hbits((_Float16)src[(size_t)dl * stride + e]);
    }
    __syncthreads();
    const int eo = tid >> 2, d16 = (tid & 3) * 16;
#pragma unroll
    for (int j = 0; j < 4; j++) {
        *(ushort4*)&WT[(size_t)(outRow0 + eo) * DD + kcol0 + d16 + j * 4] =
            *(const ushort4*)&LT[eo * 68 + d16 + j * 4];
    }
}

// ---------------------------------------------------------------------------
// fp16 MFMA GEMM: 128x128 tile, BK=64, 256 threads (4 waves, 2x2).
// Both operands k-contiguous fp16 rows (A = Xh rows, B = WT rows).
// LDS chunk = 16 rows x 32 k (512 u16 = 1KB); frag read = ds_read_b128 at
// chunk*1024B + lane*16B (conflict-free). Staging = pure 16B copies.
// ---------------------------------------------------------------------------
#define GBM 128
#define GBN 128
#define GBK 64

// Fused QKV projection. Writes q/k/v as fp16 [B,H,S,HD] + per-(b,h) max||k||^2.
__global__ __launch_bounds__(256) void qkv_gemm(
    const unsigned short* __restrict__ Xh, const unsigned short* __restrict__ WT,
    const float* __restrict__ bq, const float* __restrict__ bk,
    const float* __restrict__ bv,
    unsigned short* __restrict__ qh, unsigned short* __restrict__ kh,
    unsigned short* __restrict__ vh, unsigned int* __restrict__ kc2)
{
    __shared__ __align__(16) unsigned short As[16 * 512];
    __shared__ __align__(16) unsigned short Bs[16 * 512];

    const int tid = threadIdx.x;
    const int m0 = blockIdx.y * GBM;
    const int n0 = blockIdx.x * GBN;
    const int lane = tid & 63;
    const int w = tid >> 6;
    const int wm = w & 1, wn = w >> 1;
    const int l15 = lane & 15, quad = lane >> 4;

    // staging offsets (constant over kt): slot s = p*256+tid
    int g_off[4], l_off[4];
#pragma unroll
    for (int p = 0; p < 4; p++) {
        const int s = p * 256 + tid;
        const int c = s >> 6, j = s & 63;
        g_off[p] = ((c >> 1) * 16 + (j & 15)) * DD + (c & 1) * 32 + (j >> 4) * 8;
        l_off[p] = c * 512 + j * 8;
    }

    f32x4 acc[4][4];
#pragma unroll
    for (int i = 0; i < 4; i++)
#pragma unroll
        for (int j = 0; j < 4; j++) acc[i][j] = (f32x4){0.f, 0.f, 0.f, 0.f};

    const unsigned short* Abase = Xh + (size_t)m0 * DD;
    const unsigned short* Bbase = WT + (size_t)n0 * DD;

    for (int kt = 0; kt < DD; kt += GBK) {
        __syncthreads();   // prior iter frag reads done
#pragma unroll
        for (int p = 0; p < 4; p++) {
            *(u16x8*)&As[l_off[p]] = *(const u16x8*)&Abase[g_off[p] + kt];
            *(u16x8*)&Bs[l_off[p]] = *(const u16x8*)&Bbase[g_off[p] + kt];
        }
        __syncthreads();
#pragma unroll
        for (int ks = 0; ks < 2; ks++) {
            f16x8 af[4], bf[4];
#pragma unroll
            for (int i = 0; i < 4; i++) {
                af[i] = *(const f16x8*)&As[((wm * 4 + i) * 2 + ks) * 512 + lane * 8];
                bf[i] = *(const f16x8*)&Bs[((wn * 4 + i) * 2 + ks) * 512 + lane * 8];
            }
#pragma unroll
            for (int ns = 0; ns < 4; ns++)
#pragma unroll
                for (int ms = 0; ms < 4; ms++)
                    acc[ms][ns] = __builtin_amdgcn_mfma_f32_16x16x32_f16(
                        af[ms], bf[ns], acc[ms][ns], 0, 0, 0);
        }
    }

    // epilogue: bias + fp16 convert + scatter to [B,H,S,HD]
    const int sel = n0 >> 10;                    // block-uniform
    const int hw = ((n0 + wn * 64) >> 6) & 15;   // wave-uniform head
    const int bblk = m0 >> 11;
    const float* bias = (sel == 0) ? bq : ((sel == 1) ? bk : bv);
    unsigned short* dst = (sel == 0) ? qh : ((sel == 1) ? kh : vh);
    float wmx = 0.0f;
#pragma unroll
    for (int ms = 0; ms < 4; ms++) {
#pragma unroll
        for (int rr = 0; rr < 4; rr++) {
            const int m = m0 + wm * 64 + ms * 16 + quad * 4 + rr;
            const int s = m & (SS - 1);
            float v2 = 0.0f;
#pragma unroll
            for (int ns = 0; ns < 4; ns++) {
                const int e = ns * 16 + l15;
                const size_t ofs = (((size_t)bblk * HH + hw) * SS + s) * HD + e;
                const float val = acc[ms][ns][rr] + bias[hw * HD + e];
                if (sel == 1) v2 = fmaf(val, val, v2);
                dst[ofs] = hbits((_Float16)val);
            }
            if (sel == 1) {
                v2 += __shfl_xor(v2, 1);
                v2 += __shfl_xor(v2, 2);
                v2 += __shfl_xor(v2, 4);
                v2 += __shfl_xor(v2, 8);
                wmx = fmaxf(wmx, v2);
            }
        }
    }
    if (sel == 1) {
        wmx = fmaxf(wmx, __shfl_xor(wmx, 16));
        wmx = fmaxf(wmx, __shfl_xor(wmx, 32));
        if (lane == 0)
            atomicMax(&kc2[bblk * HH + hw], __float_as_uint(wmx));
    }
}

// Output projection: out = ctx @ Wo + bo (fp32 out).
__global__ __launch_bounds__(256) void out_gemm(
    const unsigned short* __restrict__ Ctxh, const unsigned short* __restrict__ WoT,
    const float* __restrict__ bo, float* __restrict__ out)
{
    __shared__ __align__(16) unsigned short As[16 * 512];
    __shared__ __align__(16) unsigned short Bs[16 * 512];

    const int tid = threadIdx.x;
    const int m0 = blockIdx.y * GBM;
    const int n0 = blockIdx.x * GBN;
    const int lane = tid & 63;
    const int w = tid >> 6;
    const int wm = w & 1, wn = w >> 1;
    const int l15 = lane & 15, quad = lane >> 4;

    int g_off[4], l_off[4];
#pragma unroll
    for (int p = 0; p < 4; p++) {
        const int s = p * 256 + tid;
        const int c = s >> 6, j = s & 63;
        g_off[p] = ((c >> 1) * 16 + (j & 15)) * DD + (c & 1) * 32 + (j >> 4) * 8;
        l_off[p] = c * 512 + j * 8;
    }

    f32x4 acc[4][4];
#pragma unroll
    for (int i = 0; i < 4; i++)
#pragma unroll
        for (int j = 0; j < 4; j++) acc[i][j] = (f32x4){0.f, 0.f, 0.f, 0.f};

    const unsigned short* Abase = Ctxh + (size_t)m0 * DD;
    const unsigned short* Bbase = WoT + (size_t)n0 * DD;

    for (int kt = 0; kt < DD; kt += GBK) {
        __syncthreads();
#pragma unroll
        for (int p = 0; p < 4; p++) {
            *(u16x8*)&As[l_off[p]] = *(const u16x8*)&Abase[g_off[p] + kt];
            *(u16x8*)&Bs[l_off[p]] = *(const u16x8*)&Bbase[g_off[p] + kt];
        }
        __syncthreads();
#pragma unroll
        for (int ks = 0; ks < 2; ks++) {
            f16x8 af[4], bf[4];
#pragma unroll
            for (int i = 0; i < 4; i++) {
                af[i] = *(const f16x8*)&As[((wm * 4 + i) * 2 + ks) * 512 + lane * 8];
                bf[i] = *(const f16x8*)&Bs[((wn * 4 + i) * 2 + ks) * 512 + lane * 8];
            }
#pragma unroll
            for (int ns = 0; ns < 4; ns++)
#pragma unroll
                for (int ms = 0; ms < 4; ms++)
                    acc[ms][ns] = __builtin_amdgcn_mfma_f32_16x16x32_f16(
                        af[ms], bf[ns], acc[ms][ns], 0, 0, 0);
        }
    }

#pragma unroll
    for (int ms = 0; ms < 4; ms++) {
#pragma unroll
        for (int rr = 0; rr < 4; rr++) {
            const size_t m = (size_t)(m0 + wm * 64 + ms * 16 + quad * 4 + rr);
#pragma unroll
            for (int ns = 0; ns < 4; ns++) {
                const int n = n0 + wn * 64 + ns * 16 + l15;
                out[m * DD + n] = acc[ms][ns][rr] + bo[n];
            }
        }
    }
}

// ---------------------------------------------------------------------------
// fp16 MFMA flash attention, fixed-m softmax, XOR-swizzled LDS.
// Block = 256 threads (4 waves); wave w owns 32 q rows (2 m-subtiles).
// off(row,col) = row*64 + ((col>>3 ^ (row&7))<<3) + (col&7).
// ---------------------------------------------------------------------------
#define TQB 128
#define TKB 64
#define C1 0.1803368801111204f   // 0.125 * log2(e)

__device__ __forceinline__ int swz(int row, int grp) {
    return (row << 6) + (((grp) ^ (row & 7)) << 3);
}

__global__ __launch_bounds__(256) void attn_mfma(
    const unsigned short* __restrict__ qh, const unsigned short* __restrict__ kh,
    const unsigned short* __restrict__ vh, const unsigned int* __restrict__ kc2,
    unsigned short* __restrict__ ctxh)
{
    __shared__ __align__(16) unsigned short KL [TKB * 64];
    __shared__ __align__(16) unsigned short VtL[HD * 64];
    __shared__ __align__(16) unsigned short PsL[4][32 * 64];

    const int tid  = threadIdx.x;
    const int lane = tid & 63;
    const int w    = tid >> 6;
    const int l15  = lane & 15;
    const int quad = lane >> 4;
    const int bh   = blockIdx.y;
    const int q0   = blockIdx.x * TQB;

    const float kfac = sqrtf(__uint_as_float(kc2[bh])) * 1.01f * C1;

    // ---- Q A-frags (fp16, direct 16B loads) + per-row norm -> fixed-m bound
    f16x8 qf[2][2];
    float M2r[2][4];
#pragma unroll
    for (int msub = 0; msub < 2; msub++) {
        const unsigned short* qrow =
            qh + ((size_t)bh * SS + q0 + w * 32 + msub * 16 + l15) * HD;
        float nq2 = 0.0f;
#pragma unroll
        for (int dstep = 0; dstep < 2; dstep++) {
            qf[msub][dstep] = *(const f16x8*)&qrow[dstep * 32 + quad * 8];
#pragma unroll
            for (int j = 0; j < 8; j++) {
                const float x = (float)qf[msub][dstep][j];
                nq2 = fmaf(x, x, nq2);
            }
        }
        nq2 += __shfl_xor(nq2, 16);
        nq2 += __shfl_xor(nq2, 32);
        const float M2 = sqrtf(nq2) * kfac;
#pragma unroll
        for (int rr = 0; rr < 4; rr++)
            M2r[msub][rr] = __shfl(M2, quad * 4 + rr);
    }

    f32x4 o[2][4];
    float lpart[2][4];
#pragma unroll
    for (int ms = 0; ms < 2; ms++)
#pragma unroll
        for (int e = 0; e < 4; e++) o[ms][e] = (f32x4){0.f, 0.f, 0.f, 0.f};
#pragma unroll
    for (int ms = 0; ms < 2; ms++)
#pragma unroll
        for (int rr = 0; rr < 4; rr++) lpart[ms][rr] = 0.0f;

    const int rg = tid >> 4;      // V staging: keys rg*4..+3
    const int cg = tid & 15;      //            e    cg*4..+3
    const unsigned short* kb0 = kh + (size_t)bh * SS * HD;
    const unsigned short* vb0 = vh + (size_t)bh * SS * HD;

    for (int t = 0; t < SS / TKB; t++) {
        __syncthreads();   // prior tile reads done

        // ---- stage K (swizzled, pure 16B copies)
        const unsigned short* kb = kb0 + (size_t)t * TKB * HD;
#pragma unroll
        for (int p = 0; p < 2; p++) {
            const int idx = tid + p * 256;
            const int key = idx >> 3;
            const int g = idx & 7;
            *(u16x8*)&KL[swz(key, g)] = *(const u16x8*)&kb[key * HD + g * 8];
        }
        // ---- stage V transposed (4x4 u16 repack)
        const unsigned short* vb = vb0 + (size_t)t * TKB * HD;
        u16x4 r0 = *(const u16x4*)&vb[(rg * 4 + 0) * HD + cg * 4];
        u16x4 r1 = *(const u16x4*)&vb[(rg * 4 + 1) * HD + cg * 4];
        u16x4 r2 = *(const u16x4*)&vb[(rg * 4 + 2) * HD + cg * 4];
        u16x4 r3 = *(const u16x4*)&vb[(rg * 4 + 3) * HD + cg * 4];
#pragma unroll
        for (int c = 0; c < 4; c++) {
            u16x4 tv = (u16x4){r0[c], r1[c], r2[c], r3[c]};
            *(u16x4*)&VtL[swz(cg * 4 + c, rg >> 1) + (rg & 1) * 4] = tv;
        }
        __syncthreads();

        // ---- scores: 2 MFMA per (msub,ksub)
        f32x4 sc[2][4];
#pragma unroll
        for (int ksub = 0; ksub < 4; ksub++) {
            const int row = ksub * 16 + l15;
            f16x8 k0 = *(const f16x8*)&KL[swz(row, quad)];
            f16x8 k1 = *(const f16x8*)&KL[swz(row, 4 + quad)];
#pragma unroll
            for (int msub = 0; msub < 2; msub++) {
                f32x4 a = (f32x4){0.f, 0.f, 0.f, 0.f};
                a = __builtin_amdgcn_mfma_f32_16x16x32_f16(qf[msub][0], k0, a, 0, 0, 0);
                a = __builtin_amdgcn_mfma_f32_16x16x32_f16(qf[msub][1], k1, a, 0, 0, 0);
                sc[msub][ksub] = a;
            }
        }

        // ---- fixed-m softmax; P (fp16) to wave-private swizzled LDS
#pragma unroll
        for (int msub = 0; msub < 2; msub++) {
#pragma unroll
            for (int rr = 0; rr < 4; rr++) {
                const int prow = msub * 16 + quad * 4 + rr;
#pragma unroll
                for (int ksub = 0; ksub < 4; ksub++) {
                    const float p = exp2f(fmaf(sc[msub][ksub][rr], C1, -M2r[msub][rr]));
                    const _Float16 ph = (_Float16)p;
                    lpart[msub][rr] += (float)ph;
                    PsL[w][swz(prow, ksub * 2 + (l15 >> 3)) + (l15 & 7)] = hbits(ph);
                }
            }
        }

        // ---- PV
#pragma unroll
        for (int kj = 0; kj < 2; kj++) {
            f16x8 pa[2];
#pragma unroll
            for (int msub = 0; msub < 2; msub++)
                pa[msub] = *(const f16x8*)&PsL[w][swz(msub * 16 + l15, kj * 4 + quad)];
#pragma unroll
            for (int esub = 0; esub < 4; esub++) {
                f16x8 vr = *(const f16x8*)&VtL[swz(esub * 16 + l15, kj * 4 + quad)];
                o[0][esub] = __builtin_amdgcn_mfma_f32_16x16x32_f16(pa[0], vr, o[0][esub], 0, 0, 0);
                o[1][esub] = __builtin_amdgcn_mfma_f32_16x16x32_f16(pa[1], vr, o[1][esub], 0, 0, 0);
            }
        }
    }

    // ---- deferred l + fp16 ctx epilogue ([B*S][D] head-concat layout)
    const int b = bh >> 4;
    const int h = bh & 15;
#pragma unroll
    for (int msub = 0; msub < 2; msub++) {
#pragma unroll
        for (int rr = 0; rr < 4; rr++) {
            float l = lpart[msub][rr];
            l += __shfl_xor(l, 1);
            l += __shfl_xor(l, 2);
            l += __shfl_xor(l, 4);
            l += __shfl_xor(l, 8);
            const float linv = 1.0f / l;
            const int row = q0 + w * 32 + msub * 16 + quad * 4 + rr;
#pragma unroll
            for (int esub = 0; esub < 4; esub++) {
                ctxh[((size_t)b * SS + row) * DD + h * HD + esub * 16 + l15] =
                    hbits((_Float16)(o[msub][esub][rr] * linv));
            }
        }
    }
}

// ---------------------------------------------------------------------------
extern "C" void kernel_launch(void* const* d_in, const int* in_sizes, int n_in,
                              void* d_out, int out_size, void* d_ws, size_t ws_size,
                              hipStream_t stream) {
    const float* X  = (const float*)d_in[0];
    const float* Wq = (const float*)d_in[1];
    const float* bq = (const float*)d_in[2];
    const float* Wk = (const float*)d_in[3];
    const float* bk = (const float*)d_in[4];
    const float* Wv = (const float*)d_in[5];
    const float* bv = (const float*)d_in[6];
    const float* Wo = (const float*)d_in[7];
    const float* bo = (const float*)d_in[8];
    float* out = (float*)d_out;

    // ws layout (u16 buffers, 8.39 MB each): Xh | WTall | qh | kh | vh | ctxh | kc2
    const size_t NB2 = (size_t)4096 * 1024 * 2;   // 8388608 B
    unsigned char* w8 = (unsigned char*)d_ws;
    unsigned short* Xh   = (unsigned short*)(w8);
    unsigned short* WT   = (unsigned short*)(w8 + NB2);
    unsigned short* qh   = (unsigned short*)(w8 + 2 * NB2);
    unsigned short* kh   = (unsigned short*)(w8 + 3 * NB2);
    unsigned short* vh   = (unsigned short*)(w8 + 4 * NB2);
    unsigned short* ctxh = (unsigned short*)(w8 + 5 * NB2);
    unsigned int*   kc2  = (unsigned int*)(w8 + 6 * NB2);
    unsigned short* WoT  = WT + (size_t)3072 * 1024;

    hipMemsetAsync(kc2, 0, BB * HH * sizeof(unsigned int), stream);

    // 0) convert X + transpose/convert weights to fp16
    prep_convert<<<dim3(3072), 256, 0, stream>>>(X, Wq, Wk, Wv, Wo, Xh, WT);

    // 1) fused QKV projection (fp16 MFMA): M=4096, N=3072
    qkv_gemm<<<dim3(3072 / GBN, 4096 / GBM), 256, 0, stream>>>(
        Xh, WT, bq, bk, bv, qh, kh, vh, kc2);

    // 2) MFMA flash attention (fixed-m softmax, fp16)
    attn_mfma<<<dim3(SS / TQB, BB * HH), 256, 0, stream>>>(qh, kh, vh, kc2, ctxh);

    // 3) output projection (fp16 MFMA): M=4096, N=1024
    out_gemm<<<dim3(1024 / GBN, 4096 / GBM), 256, 0, stream>>>(ctxh, WoT, bo, out);
}

// Round 7
// 267.311 us; speedup vs baseline: 5.6194x; 1.0140x over previous
//
#include <hip/hip_runtime.h>
#include <hip/hip_bf16.h>
#include <math.h>

// Problem constants
#define BB 2
#define SS 2048
#define DD 1024
#define HH 16
#define HD 64

typedef __attribute__((ext_vector_type(8))) _Float16 f16x8;
typedef __attribute__((ext_vector_type(8))) unsigned short u16x8;
typedef __attribute__((ext_vector_type(4))) float f32x4;
typedef __attribute__((ext_vector_type(4))) unsigned short u16x4;

__device__ __forceinline__ unsigned short hbits(_Float16 h) {
    union { _Float16 h; unsigned short s; } u; u.h = h; return u.s;
}

// ---------------------------------------------------------------------------
// Prepass: convert X -> fp16 (same layout) and W -> fp16 TRANSPOSED rows:
//   WTall[n][k], n in [0,3072) = (sel,h,e) qkv cols, n in [3072,4096) = Wo cols.
// ---------------------------------------------------------------------------
__global__ __launch_bounds__(256) void prep_convert(
    const float* __restrict__ X,
    const float* __restrict__ Wq, const float* __restrict__ Wk,
    const float* __restrict__ Wv, const float* __restrict__ Wo,
    unsigned short* __restrict__ Xh, unsigned short* __restrict__ WT)
{
    __shared__ __align__(16) unsigned short LT[64 * 68];
    const int bid = blockIdx.x;
    const int tid = threadIdx.x;

    if (bid < 2048) {
        const int base = bid * 2048 + tid * 8;
        float4 a = *(const float4*)&X[base];
        float4 b = *(const float4*)&X[base + 4];
        u16x8 o;
        o[0] = hbits((_Float16)a.x); o[1] = hbits((_Float16)a.y);
        o[2] = hbits((_Float16)a.z); o[3] = hbits((_Float16)a.w);
        o[4] = hbits((_Float16)b.x); o[5] = hbits((_Float16)b.y);
        o[6] = hbits((_Float16)b.z); o[7] = hbits((_Float16)b.w);
        *(u16x8*)&Xh[base] = o;
        return;
    }

    const int t = bid - 2048;
    const float* src;
    size_t stride;
    int outRow0, kcol0;
    if (t < 768) {
        const int nt = t >> 4, ktile = t & 15;
        const int sel = nt >> 4, hh = nt & 15;
        const float* Ws = (sel == 0) ? Wq : ((sel == 1) ? Wk : Wv);
        src = Ws + (size_t)hh * (DD * HD) + (size_t)ktile * 64 * HD;
        stride = HD;
        outRow0 = nt * 64;
        kcol0 = ktile * 64;
    } else {
        const int tt = t - 768;
        const int nt = tt & 15, ktile = tt >> 4;
        src = Wo + (size_t)ktile * 64 * DD + nt * 64;
        stride = DD;
        outRow0 = 3072 + nt * 64;
        kcol0 = ktile * 64;
    }

    const int e = tid & 63, dq = tid >> 6;
#pragma unroll
    for (int p = 0; p < 16; p++) {
        const int dl = p * 4 + dq;
        LT[e * 68 + dl] = hbits((_Float16)src[(size_t)dl * stride + e]);
    }
    __syncthreads();
    const int eo = tid >> 2, d16 = (tid & 3) * 16;
#pragma unroll
    for (int j = 0; j < 4; j++) {
        *(ushort4*)&WT[(size_t)(outRow0 + eo) * DD + kcol0 + d16 + j * 4] =
            *(const ushort4*)&LT[eo * 68 + d16 + j * 4];
    }
}

// ---------------------------------------------------------------------------
// fp16 MFMA GEMM: 128x128 tile, BK=64, 256 threads (4 waves, 2x2).
// ---------------------------------------------------------------------------
#define GBM 128
#define GBN 128
#define GBK 64

__global__ __launch_bounds__(256) void qkv_gemm(
    const unsigned short* __restrict__ Xh, const unsigned short* __restrict__ WT,
    const float* __restrict__ bq, const float* __restrict__ bk,
    const float* __restrict__ bv,
    unsigned short* __restrict__ qh, unsigned short* __restrict__ kh,
    unsigned short* __restrict__ vh, unsigned int* __restrict__ kc2)
{
    __shared__ __align__(16) unsigned short As[16 * 512];
    __shared__ __align__(16) unsigned short Bs[16 * 512];

    const int tid = threadIdx.x;
    const int m0 = blockIdx.y * GBM;
    const int n0 = blockIdx.x * GBN;
    const int lane = tid & 63;
    const int w = tid >> 6;
    const int wm = w & 1, wn = w >> 1;
    const int l15 = lane & 15, quad = lane >> 4;

    int g_off[4], l_off[4];
#pragma unroll
    for (int p = 0; p < 4; p++) {
        const int s = p * 256 + tid;
        const int c = s >> 6, j = s & 63;
        g_off[p] = ((c >> 1) * 16 + (j & 15)) * DD + (c & 1) * 32 + (j >> 4) * 8;
        l_off[p] = c * 512 + j * 8;
    }

    f32x4 acc[4][4];
#pragma unroll
    for (int i = 0; i < 4; i++)
#pragma unroll
        for (int j = 0; j < 4; j++) acc[i][j] = (f32x4){0.f, 0.f, 0.f, 0.f};

    const unsigned short* Abase = Xh + (size_t)m0 * DD;
    const unsigned short* Bbase = WT + (size_t)n0 * DD;

    for (int kt = 0; kt < DD; kt += GBK) {
        __syncthreads();
#pragma unroll
        for (int p = 0; p < 4; p++) {
            *(u16x8*)&As[l_off[p]] = *(const u16x8*)&Abase[g_off[p] + kt];
            *(u16x8*)&Bs[l_off[p]] = *(const u16x8*)&Bbase[g_off[p] + kt];
        }
        __syncthreads();
#pragma unroll
        for (int ks = 0; ks < 2; ks++) {
            f16x8 af[4], bf[4];
#pragma unroll
            for (int i = 0; i < 4; i++) {
                af[i] = *(const f16x8*)&As[((wm * 4 + i) * 2 + ks) * 512 + lane * 8];
                bf[i] = *(const f16x8*)&Bs[((wn * 4 + i) * 2 + ks) * 512 + lane * 8];
            }
#pragma unroll
            for (int ns = 0; ns < 4; ns++)
#pragma unroll
                for (int ms = 0; ms < 4; ms++)
                    acc[ms][ns] = __builtin_amdgcn_mfma_f32_16x16x32_f16(
                        af[ms], bf[ns], acc[ms][ns], 0, 0, 0);
        }
    }

    const int sel = n0 >> 10;
    const int hw = ((n0 + wn * 64) >> 6) & 15;
    const int bblk = m0 >> 11;
    const float* bias = (sel == 0) ? bq : ((sel == 1) ? bk : bv);
    unsigned short* dst = (sel == 0) ? qh : ((sel == 1) ? kh : vh);
    float wmx = 0.0f;
#pragma unroll
    for (int ms = 0; ms < 4; ms++) {
#pragma unroll
        for (int rr = 0; rr < 4; rr++) {
            const int m = m0 + wm * 64 + ms * 16 + quad * 4 + rr;
            const int s = m & (SS - 1);
            float v2 = 0.0f;
#pragma unroll
            for (int ns = 0; ns < 4; ns++) {
                const int e = ns * 16 + l15;
                const size_t ofs = (((size_t)bblk * HH + hw) * SS + s) * HD + e;
                const float val = acc[ms][ns][rr] + bias[hw * HD + e];
                if (sel == 1) v2 = fmaf(val, val, v2);
                dst[ofs] = hbits((_Float16)val);
            }
            if (sel == 1) {
                v2 += __shfl_xor(v2, 1);
                v2 += __shfl_xor(v2, 2);
                v2 += __shfl_xor(v2, 4);
                v2 += __shfl_xor(v2, 8);
                wmx = fmaxf(wmx, v2);
            }
        }
    }
    if (sel == 1) {
        wmx = fmaxf(wmx, __shfl_xor(wmx, 16));
        wmx = fmaxf(wmx, __shfl_xor(wmx, 32));
        if (lane == 0)
            atomicMax(&kc2[bblk * HH + hw], __float_as_uint(wmx));
    }
}

__global__ __launch_bounds__(256) void out_gemm(
    const unsigned short* __restrict__ Ctxh, const unsigned short* __restrict__ WoT,
    const float* __restrict__ bo, float* __restrict__ out)
{
    __shared__ __align__(16) unsigned short As[16 * 512];
    __shared__ __align__(16) unsigned short Bs[16 * 512];

    const int tid = threadIdx.x;
    const int m0 = blockIdx.y * GBM;
    const int n0 = blockIdx.x * GBN;
    const int lane = tid & 63;
    const int w = tid >> 6;
    const int wm = w & 1, wn = w >> 1;
    const int l15 = lane & 15, quad = lane >> 4;

    int g_off[4], l_off[4];
#pragma unroll
    for (int p = 0; p < 4; p++) {
        const int s = p * 256 + tid;
        const int c = s >> 6, j = s & 63;
        g_off[p] = ((c >> 1) * 16 + (j & 15)) * DD + (c & 1) * 32 + (j >> 4) * 8;
        l_off[p] = c * 512 + j * 8;
    }

    f32x4 acc[4][4];
#pragma unroll
    for (int i = 0; i < 4; i++)
#pragma unroll
        for (int j = 0; j < 4; j++) acc[i][j] = (f32x4){0.f, 0.f, 0.f, 0.f};

    const unsigned short* Abase = Ctxh + (size_t)m0 * DD;
    const unsigned short* Bbase = WoT + (size_t)n0 * DD;

    for (int kt = 0; kt < DD; kt += GBK) {
        __syncthreads();
#pragma unroll
        for (int p = 0; p < 4; p++) {
            *(u16x8*)&As[l_off[p]] = *(const u16x8*)&Abase[g_off[p] + kt];
            *(u16x8*)&Bs[l_off[p]] = *(const u16x8*)&Bbase[g_off[p] + kt];
        }
        __syncthreads();
#pragma unroll
        for (int ks = 0; ks < 2; ks++) {
            f16x8 af[4], bf[4];
#pragma unroll
            for (int i = 0; i < 4; i++) {
                af[i] = *(const f16x8*)&As[((wm * 4 + i) * 2 + ks) * 512 + lane * 8];
                bf[i] = *(const f16x8*)&Bs[((wn * 4 + i) * 2 + ks) * 512 + lane * 8];
            }
#pragma unroll
            for (int ns = 0; ns < 4; ns++)
#pragma unroll
                for (int ms = 0; ms < 4; ms++)
                    acc[ms][ns] = __builtin_amdgcn_mfma_f32_16x16x32_f16(
                        af[ms], bf[ns], acc[ms][ns], 0, 0, 0);
        }
    }

#pragma unroll
    for (int ms = 0; ms < 4; ms++) {
#pragma unroll
        for (int rr = 0; rr < 4; rr++) {
            const size_t m = (size_t)(m0 + wm * 64 + ms * 16 + quad * 4 + rr);
#pragma unroll
            for (int ns = 0; ns < 4; ns++) {
                const int n = n0 + wn * 64 + ns * 16 + l15;
                out[m * DD + n] = acc[ms][ns][rr] + bo[n];
            }
        }
    }
}

// ---------------------------------------------------------------------------
// fp16 MFMA flash attention, fixed-m softmax, S^T trick:
// scores computed TRANSPOSED (mfma(K,Q)) so P exits with col=q=l15 and
// 4 consecutive keys per lane -> P staged with u16x4 vector writes and read
// back as A-frag b128 (both min-cycle under the XOR swizzle).
// Block = 256 threads (4 waves); wave w owns 32 q rows (2 m-subtiles).
// off(row,col) = row*64 + ((col>>3 ^ (row&7))<<3) + (col&7).
// ---------------------------------------------------------------------------
#define TQB 128
#define TKB 64
#define C1 0.1803368801111204f   // 0.125 * log2(e)

__device__ __forceinline__ int swz(int row, int grp) {
    return (row << 6) + (((grp) ^ (row & 7)) << 3);
}

__global__ __launch_bounds__(256) void attn_mfma(
    const unsigned short* __restrict__ qh, const unsigned short* __restrict__ kh,
    const unsigned short* __restrict__ vh, const unsigned int* __restrict__ kc2,
    unsigned short* __restrict__ ctxh)
{
    __shared__ __align__(16) unsigned short KL [TKB * 64];
    __shared__ __align__(16) unsigned short VtL[HD * 64];
    __shared__ __align__(16) unsigned short PsL[4][32 * 64];

    const int tid  = threadIdx.x;
    const int lane = tid & 63;
    const int w    = tid >> 6;
    const int l15  = lane & 15;
    const int quad = lane >> 4;
    const int bh   = blockIdx.y;
    const int q0   = blockIdx.x * TQB;

    const float kfac = sqrtf(__uint_as_float(kc2[bh])) * 1.01f * C1;

    // ---- Q B-frags (lane l15 = q-row, quad = d-octet) + per-lane M2 bound.
    // After the quad-reduction every lane holds ||q_row(l15)||, which is
    // exactly the row its softmax column l15 refers to (S^T: col = q).
    f16x8 qf[2][2];
    float M2[2];
#pragma unroll
    for (int msub = 0; msub < 2; msub++) {
        const unsigned short* qrow =
            qh + ((size_t)bh * SS + q0 + w * 32 + msub * 16 + l15) * HD;
        float nq2 = 0.0f;
#pragma unroll
        for (int dstep = 0; dstep < 2; dstep++) {
            qf[msub][dstep] = *(const f16x8*)&qrow[dstep * 32 + quad * 8];
#pragma unroll
            for (int j = 0; j < 8; j++) {
                const float x = (float)qf[msub][dstep][j];
                nq2 = fmaf(x, x, nq2);
            }
        }
        nq2 += __shfl_xor(nq2, 16);
        nq2 += __shfl_xor(nq2, 32);
        M2[msub] = sqrtf(nq2) * kfac;
    }

    f32x4 o[2][4];
    float lpart[2] = {0.f, 0.f};
#pragma unroll
    for (int ms = 0; ms < 2; ms++)
#pragma unroll
        for (int e = 0; e < 4; e++) o[ms][e] = (f32x4){0.f, 0.f, 0.f, 0.f};

    const int rg = tid >> 4;      // V staging: keys rg*4..+3
    const int cg = tid & 15;      //            e    cg*4..+3
    const unsigned short* kb0 = kh + (size_t)bh * SS * HD;
    const unsigned short* vb0 = vh + (size_t)bh * SS * HD;

    for (int t = 0; t < SS / TKB; t++) {
        __syncthreads();

        // ---- stage K (swizzled, pure 16B copies)
        const unsigned short* kb = kb0 + (size_t)t * TKB * HD;
#pragma unroll
        for (int p = 0; p < 2; p++) {
            const int idx = tid + p * 256;
            const int key = idx >> 3;
            const int g = idx & 7;
            *(u16x8*)&KL[swz(key, g)] = *(const u16x8*)&kb[key * HD + g * 8];
        }
        // ---- stage V transposed (4x4 u16 repack)
        const unsigned short* vb = vb0 + (size_t)t * TKB * HD;
        u16x4 r0 = *(const u16x4*)&vb[(rg * 4 + 0) * HD + cg * 4];
        u16x4 r1 = *(const u16x4*)&vb[(rg * 4 + 1) * HD + cg * 4];
        u16x4 r2 = *(const u16x4*)&vb[(rg * 4 + 2) * HD + cg * 4];
        u16x4 r3 = *(const u16x4*)&vb[(rg * 4 + 3) * HD + cg * 4];
#pragma unroll
        for (int c = 0; c < 4; c++) {
            u16x4 tv = (u16x4){r0[c], r1[c], r2[c], r3[c]};
            *(u16x4*)&VtL[swz(cg * 4 + c, rg >> 1) + (rg & 1) * 4] = tv;
        }
        __syncthreads();

        // ---- scores TRANSPOSED: S^T = K·Q^T (A=K frag, B=Q frag).
        // C/D: row = key = ksub*16 + quad*4 + r, col = q = l15.
        f32x4 sc[2][4];
#pragma unroll
        for (int ksub = 0; ksub < 4; ksub++) {
            const int row = ksub * 16 + l15;
            f16x8 k0 = *(const f16x8*)&KL[swz(row, quad)];
            f16x8 k1 = *(const f16x8*)&KL[swz(row, 4 + quad)];
#pragma unroll
            for (int msub = 0; msub < 2; msub++) {
                f32x4 a = (f32x4){0.f, 0.f, 0.f, 0.f};
                a = __builtin_amdgcn_mfma_f32_16x16x32_f16(k0, qf[msub][0], a, 0, 0, 0);
                a = __builtin_amdgcn_mfma_f32_16x16x32_f16(k1, qf[msub][1], a, 0, 0, 0);
                sc[msub][ksub] = a;
            }
        }

        // ---- fixed-m softmax (per-lane: q = l15). P written as u16x4:
        // 4 consecutive keys (quad*4+r) at LDS row msub*16+l15.
#pragma unroll
        for (int msub = 0; msub < 2; msub++) {
            const int prow = msub * 16 + l15;
#pragma unroll
            for (int ksub = 0; ksub < 4; ksub++) {
                float p0 = exp2f(fmaf(sc[msub][ksub][0], C1, -M2[msub]));
                float p1 = exp2f(fmaf(sc[msub][ksub][1], C1, -M2[msub]));
                float p2 = exp2f(fmaf(sc[msub][ksub][2], C1, -M2[msub]));
                float p3 = exp2f(fmaf(sc[msub][ksub][3], C1, -M2[msub]));
                lpart[msub] += (p0 + p1) + (p2 + p3);
                u16x4 pw;
                pw[0] = hbits((_Float16)p0);
                pw[1] = hbits((_Float16)p1);
                pw[2] = hbits((_Float16)p2);
                pw[3] = hbits((_Float16)p3);
                *(u16x4*)&PsL[w][swz(prow, ksub * 2 + (quad >> 1)) + (quad & 1) * 4] = pw;
            }
        }

        // ---- PV: O = P·V (A = P frag: one b128 per (msub,kj); B = V^T frag)
#pragma unroll
        for (int kj = 0; kj < 2; kj++) {
            f16x8 pa[2];
#pragma unroll
            for (int msub = 0; msub < 2; msub++)
                pa[msub] = *(const f16x8*)&PsL[w][swz(msub * 16 + l15, kj * 4 + quad)];
#pragma unroll
            for (int esub = 0; esub < 4; esub++) {
                f16x8 vr = *(const f16x8*)&VtL[swz(esub * 16 + l15, kj * 4 + quad)];
                o[0][esub] = __builtin_amdgcn_mfma_f32_16x16x32_f16(pa[0], vr, o[0][esub], 0, 0, 0);
                o[1][esub] = __builtin_amdgcn_mfma_f32_16x16x32_f16(pa[1], vr, o[1][esub], 0, 0, 0);
            }
        }
    }

    // ---- deferred l (reduce over quads, then broadcast to C-layout rows)
    const int b = bh >> 4;
    const int h = bh & 15;
#pragma unroll
    for (int msub = 0; msub < 2; msub++) {
        float lf = lpart[msub];
        lf += __shfl_xor(lf, 16);
        lf += __shfl_xor(lf, 32);   // now lane l15 holds l for q-row l15
#pragma unroll
        for (int rr = 0; rr < 4; rr++) {
            const float lr = __shfl(lf, quad * 4 + rr);
            const float linv = 1.0f / lr;
            const int row = q0 + w * 32 + msub * 16 + quad * 4 + rr;
#pragma unroll
            for (int esub = 0; esub < 4; esub++) {
                ctxh[((size_t)b * SS + row) * DD + h * HD + esub * 16 + l15] =
                    hbits((_Float16)(o[msub][esub][rr] * linv));
            }
        }
    }
}

// ---------------------------------------------------------------------------
extern "C" void kernel_launch(void* const* d_in, const int* in_sizes, int n_in,
                              void* d_out, int out_size, void* d_ws, size_t ws_size,
                              hipStream_t stream) {
    const float* X  = (const float*)d_in[0];
    const float* Wq = (const float*)d_in[1];
    const float* bq = (const float*)d_in[2];
    const float* Wk = (const float*)d_in[3];
    const float* bk = (const float*)d_in[4];
    const float* Wv = (const float*)d_in[5];
    const float* bv = (const float*)d_in[6];
    const float* Wo = (const float*)d_in[7];
    const float* bo = (const float*)d_in[8];
    float* out = (float*)d_out;

    // ws layout (u16 buffers, 8.39 MB each): Xh | WTall | qh | kh | vh | ctxh | kc2
    const size_t NB2 = (size_t)4096 * 1024 * 2;   // 8388608 B
    unsigned char* w8 = (unsigned char*)d_ws;
    unsigned short* Xh   = (unsigned short*)(w8);
    unsigned short* WT   = (unsigned short*)(w8 + NB2);
    unsigned short* qh   = (unsigned short*)(w8 + 2 * NB2);
    unsigned short* kh   = (unsigned short*)(w8 + 3 * NB2);
    unsigned short* vh   = (unsigned short*)(w8 + 4 * NB2);
    unsigned short* ctxh = (unsigned short*)(w8 + 5 * NB2);
    unsigned int*   kc2  = (unsigned int*)(w8 + 6 * NB2);
    unsigned short* WoT  = WT + (size_t)3072 * 1024;

    hipMemsetAsync(kc2, 0, BB * HH * sizeof(unsigned int), stream);

    // 0) convert X + transpose/convert weights to fp16
    prep_convert<<<dim3(3072), 256, 0, stream>>>(X, Wq, Wk, Wv, Wo, Xh, WT);

    // 1) fused QKV projection (fp16 MFMA): M=4096, N=3072
    qkv_gemm<<<dim3(3072 / GBN, 4096 / GBM), 256, 0, stream>>>(
        Xh, WT, bq, bk, bv, qh, kh, vh, kc2);

    // 2) MFMA flash attention (S^T, fixed-m softmax)
    attn_mfma<<<dim3(SS / TQB, BB * HH), 256, 0, stream>>>(qh, kh, vh, kc2, ctxh);

    // 3) output projection (fp16 MFMA): M=4096, N=1024
    out_gemm<<<dim3(1024 / GBN, 4096 / GBM), 256, 0, stream>>>(ctxh, WoT, bo, out);
}

// Round 9
// 241.252 us; speedup vs baseline: 6.2264x; 1.1080x over previous
//
#include <hip/hip_runtime.h>
#include <hip/hip_bf16.h>
#include <math.h>

// Problem constants
#define BB 2
#define SS 2048
#define DD 1024
#define HH 16
#define HD 64

typedef __attribute__((ext_vector_type(8))) _Float16 f16x8;
typedef __attribute__((ext_vector_type(2))) __fp16 fp16x2;
typedef __attribute__((ext_vector_type(8))) unsigned short u16x8;
typedef __attribute__((ext_vector_type(4))) float f32x4;
typedef __attribute__((ext_vector_type(4))) unsigned short u16x4;

__device__ __forceinline__ unsigned short hbits(_Float16 h) {
    union { _Float16 h; unsigned short s; } u; u.h = h; return u.s;
}

// XOR-swizzled 64x64 fp16 tile: off(row, col) = row*64 + ((col>>3 ^ row&7)<<3) + col&7
__device__ __forceinline__ int swz(int row, int grp) {
    return (row << 6) + (((grp) ^ (row & 7)) << 3);
}

__device__ __forceinline__ float fexp2(float x) {
#if __has_builtin(__builtin_amdgcn_exp2f)
    return __builtin_amdgcn_exp2f(x);
#else
    return exp2f(x);
#endif
}

__device__ __forceinline__ u16x4 pack4(float p0, float p1, float p2, float p3) {
#if __has_builtin(__builtin_amdgcn_cvt_pkrtz)
    union { fp16x2 h[2]; u16x4 u; } pu;
    pu.h[0] = __builtin_amdgcn_cvt_pkrtz(p0, p1);
    pu.h[1] = __builtin_amdgcn_cvt_pkrtz(p2, p3);
    return pu.u;
#else
    u16x4 r;
    r[0] = hbits((_Float16)p0); r[1] = hbits((_Float16)p1);
    r[2] = hbits((_Float16)p2); r[3] = hbits((_Float16)p3);
    return r;
#endif
}

// async global->LDS 16B/lane. Builtin path: lds dest = wave-uniform base + lane*16.
// g is the PER-LANE global source; l must be the wave-uniform LDS base.
__device__ __forceinline__ void gload_lds16(const unsigned short* g, unsigned short* l) {
#if __has_builtin(__builtin_amdgcn_global_load_lds)
    auto gp = (const __attribute__((address_space(1))) unsigned int*)(uintptr_t)g;
    auto lp = (__attribute__((address_space(3))) unsigned int*)(uintptr_t)l;
    __builtin_amdgcn_global_load_lds(gp, lp, 16, 0, 0);
#else
    *(u16x8*)(l + (threadIdx.x & 63) * 8) = *(const u16x8*)g;
#endif
}

// ---------------------------------------------------------------------------
// Prepass: X -> fp16 (same layout); W -> fp16 transposed rows WT[n][k].
// ---------------------------------------------------------------------------
__global__ __launch_bounds__(256) void prep_convert(
    const float* __restrict__ X,
    const float* __restrict__ Wq, const float* __restrict__ Wk,
    const float* __restrict__ Wv, const float* __restrict__ Wo,
    unsigned short* __restrict__ Xh, unsigned short* __restrict__ WT)
{
    __shared__ __align__(16) unsigned short LT[64 * 68];
    const int bid = blockIdx.x;
    const int tid = threadIdx.x;

    if (bid < 2048) {
        const int base = bid * 2048 + tid * 8;
        float4 a = *(const float4*)&X[base];
        float4 b = *(const float4*)&X[base + 4];
        u16x8 o;
        o[0] = hbits((_Float16)a.x); o[1] = hbits((_Float16)a.y);
        o[2] = hbits((_Float16)a.z); o[3] = hbits((_Float16)a.w);
        o[4] = hbits((_Float16)b.x); o[5] = hbits((_Float16)b.y);
        o[6] = hbits((_Float16)b.z); o[7] = hbits((_Float16)b.w);
        *(u16x8*)&Xh[base] = o;
        return;
    }

    const int t = bid - 2048;
    const float* src;
    size_t stride;
    int outRow0, kcol0;
    if (t < 768) {
        const int nt = t >> 4, ktile = t & 15;
        const int sel = nt >> 4, hh = nt & 15;
        const float* Ws = (sel == 0) ? Wq : ((sel == 1) ? Wk : Wv);
        src = Ws + (size_t)hh * (DD * HD) + (size_t)ktile * 64 * HD;
        stride = HD;
        outRow0 = nt * 64;
        kcol0 = ktile * 64;
    } else {
        const int tt = t - 768;
        const int nt = tt & 15, ktile = tt >> 4;
        src = Wo + (size_t)ktile * 64 * DD + nt * 64;
        stride = DD;
        outRow0 = 3072 + nt * 64;
        kcol0 = ktile * 64;
    }

    const int e = tid & 63, dq = tid >> 6;
#pragma unroll
    for (int p = 0; p < 16; p++) {
        const int dl = p * 4 + dq;
        LT[e * 68 + dl] = hbits((_Float16)src[(size_t)dl * stride + e]);
    }
    __syncthreads();
    const int eo = tid >> 2, d16 = (tid & 3) * 16;
#pragma unroll
    for (int j = 0; j < 4; j++) {
        *(ushort4*)&WT[(size_t)(outRow0 + eo) * DD + kcol0 + d16 + j * 4] =
            *(const ushort4*)&LT[eo * 68 + d16 + j * 4];
    }
}

// ---------------------------------------------------------------------------
// V transpose pass: vh [bh][s][e] -> vTs [bh][tile][ swz(e, key>>3) + key&7 ]
// (64 keys x 64 e per tile, stored e-major, swizzled for conflict-free frags)
// ---------------------------------------------------------------------------
__global__ __launch_bounds__(256) void vtrans(
    const unsigned short* __restrict__ vh, unsigned short* __restrict__ vTs)
{
    __shared__ __align__(16) unsigned short LT[64 * 72];
    const int bh = blockIdx.x >> 5;
    const int tile = blockIdx.x & 31;
    const int tid = threadIdx.x;
    const unsigned short* src = vh + (size_t)bh * SS * HD + (size_t)tile * 64 * HD;
    unsigned short* dst = vTs + (size_t)bh * SS * HD + (size_t)tile * 4096;

#pragma unroll
    for (int p = 0; p < 2; p++) {
        const int idx8 = p * 256 + tid;
        const int key = idx8 >> 3, d8 = (idx8 & 7) * 8;
        *(u16x8*)&LT[key * 72 + d8] = *(const u16x8*)&src[key * HD + d8];
    }
    __syncthreads();
#pragma unroll
    for (int p = 0; p < 2; p++) {
        const int o8 = p * 256 + tid;
        const int e = o8 >> 3, q8 = o8 & 7;
        const int g = q8 ^ (e & 7);
        u16x8 v;
#pragma unroll
        for (int j = 0; j < 8; j++)
            v[j] = LT[(g * 8 + j) * 72 + e];
        *(u16x8*)&dst[o8 * 8] = v;
    }
}

// ---------------------------------------------------------------------------
// fp16 MFMA GEMM: 128x128 tile, BK=64, 256 threads (4 waves, 2x2),
// global_load_lds (16B) staging directly into frag-chunked LDS.
// ---------------------------------------------------------------------------
#define GBM 128
#define GBN 128
#define GBK 64

__global__ __launch_bounds__(256) void qkv_gemm(
    const unsigned short* __restrict__ Xh, const unsigned short* __restrict__ WT,
    const float* __restrict__ bq, const float* __restrict__ bk,
    const float* __restrict__ bv,
    unsigned short* __restrict__ qh, unsigned short* __restrict__ kh,
    unsigned short* __restrict__ vh, unsigned int* __restrict__ kc2)
{
    __shared__ __align__(16) unsigned short As[16 * 512];
    __shared__ __align__(16) unsigned short Bs[16 * 512];

    const int tid = threadIdx.x;
    const int m0 = blockIdx.y * GBM;
    const int n0 = blockIdx.x * GBN;
    const int lane = tid & 63;
    const int w = tid >> 6;
    const int wm = w & 1, wn = w >> 1;
    const int l15 = lane & 15, quad = lane >> 4;

    // staging: chunk c = p*4+w (wave-uniform), lane covers 16 rows x (32k half)
    int g_off[4];
#pragma unroll
    for (int p = 0; p < 4; p++) {
        const int c = p * 4 + w;
        g_off[p] = ((c >> 1) * 16 + (lane & 15)) * DD + (c & 1) * 32 + (lane >> 4) * 8;
    }

    f32x4 acc[4][4];
#pragma unroll
    for (int i = 0; i < 4; i++)
#pragma unroll
        for (int j = 0; j < 4; j++) acc[i][j] = (f32x4){0.f, 0.f, 0.f, 0.f};

    const unsigned short* Abase = Xh + (size_t)m0 * DD;
    const unsigned short* Bbase = WT + (size_t)n0 * DD;

    for (int kt = 0; kt < DD; kt += GBK) {
        __syncthreads();
#pragma unroll
        for (int p = 0; p < 4; p++) {
            gload_lds16(Abase + g_off[p] + kt, &As[(p * 4 + w) * 512]);
            gload_lds16(Bbase + g_off[p] + kt, &Bs[(p * 4 + w) * 512]);
        }
        __syncthreads();
#pragma unroll
        for (int ks = 0; ks < 2; ks++) {
            f16x8 af[4], bf[4];
#pragma unroll
            for (int i = 0; i < 4; i++) {
                af[i] = *(const f16x8*)&As[((wm * 4 + i) * 2 + ks) * 512 + lane * 8];
                bf[i] = *(const f16x8*)&Bs[((wn * 4 + i) * 2 + ks) * 512 + lane * 8];
            }
#pragma unroll
            for (int ns = 0; ns < 4; ns++)
#pragma unroll
                for (int ms = 0; ms < 4; ms++)
                    acc[ms][ns] = __builtin_amdgcn_mfma_f32_16x16x32_f16(
                        af[ms], bf[ns], acc[ms][ns], 0, 0, 0);
        }
    }

    // epilogue: bias + fp16; q,v linear [B,H,S,HD]; k PRE-SWIZZLED 64x64 tiles.
    const int sel = n0 >> 10;
    const int hw = ((n0 + wn * 64) >> 6) & 15;
    const int bblk = m0 >> 11;
    const float* bias = (sel == 0) ? bq : ((sel == 1) ? bk : bv);
    const size_t bh_base = ((size_t)bblk * HH + hw) * SS * HD;
    float wmx = 0.0f;
#pragma unroll
    for (int ms = 0; ms < 4; ms++) {
#pragma unroll
        for (int rr = 0; rr < 4; rr++) {
            const int m = m0 + wm * 64 + ms * 16 + quad * 4 + rr;
            const int s = m & (SS - 1);
            float v2 = 0.0f;
#pragma unroll
            for (int ns = 0; ns < 4; ns++) {
                const int e = ns * 16 + l15;
                const float val = acc[ms][ns][rr] + bias[hw * HD + e];
                if (sel == 0) {
                    qh[bh_base + (size_t)s * HD + e] = hbits((_Float16)val);
                } else if (sel == 1) {
                    v2 = fmaf(val, val, v2);
                    const size_t kofs = bh_base + (size_t)(s >> 6) * 4096
                                      + swz(s & 63, e >> 3) + (e & 7);
                    kh[kofs] = hbits((_Float16)val);
                } else {
                    vh[bh_base + (size_t)s * HD + e] = hbits((_Float16)val);
                }
            }
            if (sel == 1) {
                v2 += __shfl_xor(v2, 1);
                v2 += __shfl_xor(v2, 2);
                v2 += __shfl_xor(v2, 4);
                v2 += __shfl_xor(v2, 8);
                wmx = fmaxf(wmx, v2);
            }
        }
    }
    if (sel == 1) {
        wmx = fmaxf(wmx, __shfl_xor(wmx, 16));
        wmx = fmaxf(wmx, __shfl_xor(wmx, 32));
        if (lane == 0)
            atomicMax(&kc2[bblk * HH + hw], __float_as_uint(wmx));
    }
}

__global__ __launch_bounds__(256) void out_gemm(
    const unsigned short* __restrict__ Ctxh, const unsigned short* __restrict__ WoT,
    const float* __restrict__ bo, float* __restrict__ out)
{
    __shared__ __align__(16) unsigned short As[16 * 512];
    __shared__ __align__(16) unsigned short Bs[16 * 512];

    const int tid = threadIdx.x;
    const int m0 = blockIdx.y * GBM;
    const int n0 = blockIdx.x * GBN;
    const int lane = tid & 63;
    const int w = tid >> 6;
    const int wm = w & 1, wn = w >> 1;
    const int l15 = lane & 15, quad = lane >> 4;

    int g_off[4];
#pragma unroll
    for (int p = 0; p < 4; p++) {
        const int c = p * 4 + w;
        g_off[p] = ((c >> 1) * 16 + (lane & 15)) * DD + (c & 1) * 32 + (lane >> 4) * 8;
    }

    f32x4 acc[4][4];
#pragma unroll
    for (int i = 0; i < 4; i++)
#pragma unroll
        for (int j = 0; j < 4; j++) acc[i][j] = (f32x4){0.f, 0.f, 0.f, 0.f};

    const unsigned short* Abase = Ctxh + (size_t)m0 * DD;
    const unsigned short* Bbase = WoT + (size_t)n0 * DD;

    for (int kt = 0; kt < DD; kt += GBK) {
        __syncthreads();
#pragma unroll
        for (int p = 0; p < 4; p++) {
            gload_lds16(Abase + g_off[p] + kt, &As[(p * 4 + w) * 512]);
            gload_lds16(Bbase + g_off[p] + kt, &Bs[(p * 4 + w) * 512]);
        }
        __syncthreads();
#pragma unroll
        for (int ks = 0; ks < 2; ks++) {
            f16x8 af[4], bf[4];
#pragma unroll
            for (int i = 0; i < 4; i++) {
                af[i] = *(const f16x8*)&As[((wm * 4 + i) * 2 + ks) * 512 + lane * 8];
                bf[i] = *(const f16x8*)&Bs[((wn * 4 + i) * 2 + ks) * 512 + lane * 8];
            }
#pragma unroll
            for (int ns = 0; ns < 4; ns++)
#pragma unroll
                for (int ms = 0; ms < 4; ms++)
                    acc[ms][ns] = __builtin_amdgcn_mfma_f32_16x16x32_f16(
                        af[ms], bf[ns], acc[ms][ns], 0, 0, 0);
        }
    }

#pragma unroll
    for (int ms = 0; ms < 4; ms++) {
#pragma unroll
        for (int rr = 0; rr < 4; rr++) {
            const size_t m = (size_t)(m0 + wm * 64 + ms * 16 + quad * 4 + rr);
#pragma unroll
            for (int ns = 0; ns < 4; ns++) {
                const int n = n0 + wn * 64 + ns * 16 + l15;
                out[m * DD + n] = acc[ms][ns][rr] + bo[n];
            }
        }
    }
}

// ---------------------------------------------------------------------------
// fp16 MFMA flash attention (S^T), fixed-m softmax, DMA staging from
// pre-swizzled K / V^T global tiles, l via ones-MFMA.
// Block = 256 threads (4 waves); wave w owns 32 q rows.
// ---------------------------------------------------------------------------
#define TQB 128
#define TKB 64
#define C1 0.1803368801111204f   // 0.125 * log2(e)

__global__ __launch_bounds__(256) void attn_mfma(
    const unsigned short* __restrict__ qh, const unsigned short* __restrict__ kh,
    const unsigned short* __restrict__ vTs, const unsigned int* __restrict__ kc2,
    unsigned short* __restrict__ ctxh)
{
    __shared__ __align__(16) unsigned short KL [TKB * 64];
    __shared__ __align__(16) unsigned short VtL[HD * 64];
    __shared__ __align__(16) unsigned short PsL[4][32 * 64];

    const int tid  = threadIdx.x;
    const int lane = tid & 63;
    const int w    = tid >> 6;
    const int l15  = lane & 15;
    const int quad = lane >> 4;
    const int bh   = blockIdx.y;
    const int q0   = blockIdx.x * TQB;

    const float kfac = sqrtf(__uint_as_float(kc2[bh])) * 1.01f * C1;

    // Q B-frags (lane l15 = q-row, quad = d-octet) + per-lane fixed-m bound
    f16x8 qf[2][2];
    float M2[2];
#pragma unroll
    for (int msub = 0; msub < 2; msub++) {
        const unsigned short* qrow =
            qh + ((size_t)bh * SS + q0 + w * 32 + msub * 16 + l15) * HD;
        float nq2 = 0.0f;
#pragma unroll
        for (int dstep = 0; dstep < 2; dstep++) {
            qf[msub][dstep] = *(const f16x8*)&qrow[dstep * 32 + quad * 8];
#pragma unroll
            for (int j = 0; j < 8; j++) {
                const float x = (float)qf[msub][dstep][j];
                nq2 = fmaf(x, x, nq2);
            }
        }
        nq2 += __shfl_xor(nq2, 16);
        nq2 += __shfl_xor(nq2, 32);
        M2[msub] = sqrtf(nq2) * kfac;
    }

    f16x8 ones;
#pragma unroll
    for (int j = 0; j < 8; j++) ones[j] = (_Float16)1.0f;

    f32x4 o[2][4], lones[2];
#pragma unroll
    for (int ms = 0; ms < 2; ms++) {
        lones[ms] = (f32x4){0.f, 0.f, 0.f, 0.f};
#pragma unroll
        for (int e = 0; e < 4; e++) o[ms][e] = (f32x4){0.f, 0.f, 0.f, 0.f};
    }

    const unsigned short* kb0 = kh  + (size_t)bh * SS * HD;
    const unsigned short* vb0 = vTs + (size_t)bh * SS * HD;

    for (int t = 0; t < SS / TKB; t++) {
        __syncthreads();   // prior tile reads done

        // ---- DMA staging (identity layout: global tiles are pre-swizzled)
        const unsigned short* kb = kb0 + (size_t)t * 4096;
        const unsigned short* vb = vb0 + (size_t)t * 4096;
        gload_lds16(kb + tid * 8,        &KL [w * 512]);
        gload_lds16(kb + 2048 + tid * 8, &KL [2048 + w * 512]);
        gload_lds16(vb + tid * 8,        &VtL[w * 512]);
        gload_lds16(vb + 2048 + tid * 8, &VtL[2048 + w * 512]);
        __syncthreads();

        // ---- scores TRANSPOSED: S^T = K·Q^T; C/D row = key, col = q = l15
        f32x4 sc[2][4];
#pragma unroll
        for (int ksub = 0; ksub < 4; ksub++) {
            const int row = ksub * 16 + l15;
            f16x8 k0 = *(const f16x8*)&KL[swz(row, quad)];
            f16x8 k1 = *(const f16x8*)&KL[swz(row, 4 + quad)];
#pragma unroll
            for (int msub = 0; msub < 2; msub++) {
                f32x4 a = (f32x4){0.f, 0.f, 0.f, 0.f};
                a = __builtin_amdgcn_mfma_f32_16x16x32_f16(k0, qf[msub][0], a, 0, 0, 0);
                a = __builtin_amdgcn_mfma_f32_16x16x32_f16(k1, qf[msub][1], a, 0, 0, 0);
                sc[msub][ksub] = a;
            }
        }

        // ---- fixed-m softmax (per-lane q = l15), packed f16 P
#pragma unroll
        for (int msub = 0; msub < 2; msub++) {
            const int prow = msub * 16 + l15;
#pragma unroll
            for (int ksub = 0; ksub < 4; ksub++) {
                const float p0 = fexp2(fmaf(sc[msub][ksub][0], C1, -M2[msub]));
                const float p1 = fexp2(fmaf(sc[msub][ksub][1], C1, -M2[msub]));
                const float p2 = fexp2(fmaf(sc[msub][ksub][2], C1, -M2[msub]));
                const float p3 = fexp2(fmaf(sc[msub][ksub][3], C1, -M2[msub]));
                *(u16x4*)&PsL[w][swz(prow, ksub * 2 + (quad >> 1)) + (quad & 1) * 4] =
                    pack4(p0, p1, p2, p3);
            }
        }

        // ---- PV + l via ones-MFMA (PsL wave-private: no barrier)
#pragma unroll
        for (int kj = 0; kj < 2; kj++) {
            f16x8 pa[2];
#pragma unroll
            for (int msub = 0; msub < 2; msub++)
                pa[msub] = *(const f16x8*)&PsL[w][swz(msub * 16 + l15, kj * 4 + quad)];
            lones[0] = __builtin_amdgcn_mfma_f32_16x16x32_f16(pa[0], ones, lones[0], 0, 0, 0);
            lones[1] = __builtin_amdgcn_mfma_f32_16x16x32_f16(pa[1], ones, lones[1], 0, 0, 0);
#pragma unroll
            for (int esub = 0; esub < 4; esub++) {
                f16x8 vr = *(const f16x8*)&VtL[swz(esub * 16 + l15, kj * 4 + quad)];
                o[0][esub] = __builtin_amdgcn_mfma_f32_16x16x32_f16(pa[0], vr, o[0][esub], 0, 0, 0);
                o[1][esub] = __builtin_amdgcn_mfma_f32_16x16x32_f16(pa[1], vr, o[1][esub], 0, 0, 0);
            }
        }
    }

    // ---- epilogue: l sits in the same C-layout rows as o — no shuffles
    const int b = bh >> 4;
    const int h = bh & 15;
#pragma unroll
    for (int msub = 0; msub < 2; msub++) {
#pragma unroll
        for (int rr = 0; rr < 4; rr++) {
            const float linv = 1.0f / lones[msub][rr];
            const int row = q0 + w * 32 + msub * 16 + quad * 4 + rr;
#pragma unroll
            for (int esub = 0; esub < 4; esub++) {
                ctxh[((size_t)b * SS + row) * DD + h * HD + esub * 16 + l15] =
                    hbits((_Float16)(o[msub][esub][rr] * linv));
            }
        }
    }
}

// ---------------------------------------------------------------------------
extern "C" void kernel_launch(void* const* d_in, const int* in_sizes, int n_in,
                              void* d_out, int out_size, void* d_ws, size_t ws_size,
                              hipStream_t stream) {
    const float* X  = (const float*)d_in[0];
    const float* Wq = (const float*)d_in[1];
    const float* bq = (const float*)d_in[2];
    const float* Wk = (const float*)d_in[3];
    const float* bk = (const float*)d_in[4];
    const float* Wv = (const float*)d_in[5];
    const float* bv = (const float*)d_in[6];
    const float* Wo = (const float*)d_in[7];
    const float* bo = (const float*)d_in[8];
    float* out = (float*)d_out;

    // ws: Xh | WT(3072+1024 rows) | qh | kh(swz) | vh | vTs(swz) | ctxh | kc2
    const size_t NB2 = (size_t)4096 * 1024 * 2;   // 8388608 B
    unsigned char* w8 = (unsigned char*)d_ws;
    unsigned short* Xh   = (unsigned short*)(w8);
    unsigned short* WT   = (unsigned short*)(w8 + NB2);
    unsigned short* qh   = (unsigned short*)(w8 + 2 * NB2);
    unsigned short* kh   = (unsigned short*)(w8 + 3 * NB2);
    unsigned short* vh   = (unsigned short*)(w8 + 4 * NB2);
    unsigned short* vTs  = (unsigned short*)(w8 + 5 * NB2);
    unsigned short* ctxh = (unsigned short*)(w8 + 6 * NB2);
    unsigned int*   kc2  = (unsigned int*)(w8 + 7 * NB2);
    unsigned short* WoT  = WT + (size_t)3072 * 1024;

    (void)hipMemsetAsync(kc2, 0, BB * HH * sizeof(unsigned int), stream);

    // 0) convert X + transpose/convert weights to fp16
    prep_convert<<<dim3(3072), 256, 0, stream>>>(X, Wq, Wk, Wv, Wo, Xh, WT);

    // 1) fused QKV projection (fp16 MFMA, DMA staging)
    qkv_gemm<<<dim3(3072 / GBN, 4096 / GBM), 256, 0, stream>>>(
        Xh, WT, bq, bk, bv, qh, kh, vh, kc2);

    // 2) V transpose into swizzled tiles
    vtrans<<<dim3(BB * HH * 32), 256, 0, stream>>>(vh, vTs);

    // 3) MFMA flash attention (S^T, fixed-m softmax, DMA staging)
    attn_mfma<<<dim3(SS / TQB, BB * HH), 256, 0, stream>>>(qh, kh, vTs, kc2, ctxh);

    // 4) output projection (fp16 MFMA, DMA staging)
    out_gemm<<<dim3(1024 / GBN, 4096 / GBM), 256, 0, stream>>>(ctxh, WoT, bo, out);
}

// Round 10
// 235.450 us; speedup vs baseline: 6.3798x; 1.0246x over previous
//
#include <hip/hip_runtime.h>
#include <hip/hip_bf16.h>
#include <math.h>

// Problem constants
#define BB 2
#define SS 2048
#define DD 1024
#define HH 16
#define HD 64

typedef __attribute__((ext_vector_type(8))) _Float16 f16x8;
typedef __attribute__((ext_vector_type(2))) __fp16 fp16x2;
typedef __attribute__((ext_vector_type(8))) unsigned short u16x8;
typedef __attribute__((ext_vector_type(4))) float f32x4;
typedef __attribute__((ext_vector_type(4))) unsigned short u16x4;

__device__ __forceinline__ unsigned short hbits(_Float16 h) {
    union { _Float16 h; unsigned short s; } u; u.h = h; return u.s;
}

// XOR-swizzled 64x64 fp16 tile: off(row, col) = row*64 + ((col>>3 ^ row&7)<<3) + col&7
__device__ __forceinline__ int swz(int row, int grp) {
    return (row << 6) + (((grp) ^ (row & 7)) << 3);
}

__device__ __forceinline__ float fexp2(float x) {
#if __has_builtin(__builtin_amdgcn_exp2f)
    return __builtin_amdgcn_exp2f(x);
#else
    return exp2f(x);
#endif
}

__device__ __forceinline__ u16x4 pack4(float p0, float p1, float p2, float p3) {
#if __has_builtin(__builtin_amdgcn_cvt_pkrtz)
    union { fp16x2 h[2]; u16x4 u; } pu;
    pu.h[0] = __builtin_amdgcn_cvt_pkrtz(p0, p1);
    pu.h[1] = __builtin_amdgcn_cvt_pkrtz(p2, p3);
    return pu.u;
#else
    u16x4 r;
    r[0] = hbits((_Float16)p0); r[1] = hbits((_Float16)p1);
    r[2] = hbits((_Float16)p2); r[3] = hbits((_Float16)p3);
    return r;
#endif
}

// async global->LDS 16B/lane: lds dest = wave-uniform base + lane*16.
__device__ __forceinline__ void gload_lds16(const unsigned short* g, unsigned short* l) {
#if __has_builtin(__builtin_amdgcn_global_load_lds)
    auto gp = (const __attribute__((address_space(1))) unsigned int*)(uintptr_t)g;
    auto lp = (__attribute__((address_space(3))) unsigned int*)(uintptr_t)l;
    __builtin_amdgcn_global_load_lds(gp, lp, 16, 0, 0);
#else
    *(u16x8*)(l + (threadIdx.x & 63) * 8) = *(const u16x8*)g;
#endif
}

// ---------------------------------------------------------------------------
// Prepass: X -> fp16 (same layout); W -> fp16 transposed rows WT[n][k].
// ---------------------------------------------------------------------------
__global__ __launch_bounds__(256) void prep_convert(
    const float* __restrict__ X,
    const float* __restrict__ Wq, const float* __restrict__ Wk,
    const float* __restrict__ Wv, const float* __restrict__ Wo,
    unsigned short* __restrict__ Xh, unsigned short* __restrict__ WT)
{
    __shared__ __align__(16) unsigned short LT[64 * 68];
    const int bid = blockIdx.x;
    const int tid = threadIdx.x;

    if (bid < 2048) {
        const int base = bid * 2048 + tid * 8;
        float4 a = *(const float4*)&X[base];
        float4 b = *(const float4*)&X[base + 4];
        u16x8 o;
        o[0] = hbits((_Float16)a.x); o[1] = hbits((_Float16)a.y);
        o[2] = hbits((_Float16)a.z); o[3] = hbits((_Float16)a.w);
        o[4] = hbits((_Float16)b.x); o[5] = hbits((_Float16)b.y);
        o[6] = hbits((_Float16)b.z); o[7] = hbits((_Float16)b.w);
        *(u16x8*)&Xh[base] = o;
        return;
    }

    const int t = bid - 2048;
    const float* src;
    size_t stride;
    int outRow0, kcol0;
    if (t < 768) {
        const int nt = t >> 4, ktile = t & 15;
        const int sel = nt >> 4, hh = nt & 15;
        const float* Ws = (sel == 0) ? Wq : ((sel == 1) ? Wk : Wv);
        src = Ws + (size_t)hh * (DD * HD) + (size_t)ktile * 64 * HD;
        stride = HD;
        outRow0 = nt * 64;
        kcol0 = ktile * 64;
    } else {
        const int tt = t - 768;
        const int nt = tt & 15, ktile = tt >> 4;
        src = Wo + (size_t)ktile * 64 * DD + nt * 64;
        stride = DD;
        outRow0 = 3072 + nt * 64;
        kcol0 = ktile * 64;
    }

    const int e = tid & 63, dq = tid >> 6;
#pragma unroll
    for (int p = 0; p < 16; p++) {
        const int dl = p * 4 + dq;
        LT[e * 68 + dl] = hbits((_Float16)src[(size_t)dl * stride + e]);
    }
    __syncthreads();
    const int eo = tid >> 2, d16 = (tid & 3) * 16;
#pragma unroll
    for (int j = 0; j < 4; j++) {
        *(ushort4*)&WT[(size_t)(outRow0 + eo) * DD + kcol0 + d16 + j * 4] =
            *(const ushort4*)&LT[eo * 68 + d16 + j * 4];
    }
}

// ---------------------------------------------------------------------------
// fp16 MFMA GEMM: 128x128 tile, BK=64, 256 threads (4 waves, 2x2),
// DOUBLE-BUFFERED global_load_lds: DMA for tile t+1 issued before compute(t),
// so the barrier's vmcnt drain overlaps a full compute phase.
// ---------------------------------------------------------------------------
#define GBM 128
#define GBN 128
#define GBK 64
#define NKT (DD / GBK)   // 16

__global__ __launch_bounds__(256) void qkv_gemm(
    const unsigned short* __restrict__ Xh, const unsigned short* __restrict__ WT,
    const float* __restrict__ bq, const float* __restrict__ bk,
    const float* __restrict__ bv,
    unsigned short* __restrict__ qh, unsigned short* __restrict__ kh,
    unsigned short* __restrict__ vTs, unsigned int* __restrict__ kc2)
{
    __shared__ __align__(16) unsigned short As[2][16 * 512];
    __shared__ __align__(16) unsigned short Bs[2][16 * 512];

    const int tid = threadIdx.x;
    const int m0 = blockIdx.y * GBM;
    const int n0 = blockIdx.x * GBN;
    const int lane = tid & 63;
    const int w = tid >> 6;
    const int wm = w & 1, wn = w >> 1;
    const int l15 = lane & 15, quad = lane >> 4;

    int g_off[4];
#pragma unroll
    for (int p = 0; p < 4; p++) {
        const int c = p * 4 + w;
        g_off[p] = ((c >> 1) * 16 + (lane & 15)) * DD + (c & 1) * 32 + (lane >> 4) * 8;
    }

    f32x4 acc[4][4];
#pragma unroll
    for (int i = 0; i < 4; i++)
#pragma unroll
        for (int j = 0; j < 4; j++) acc[i][j] = (f32x4){0.f, 0.f, 0.f, 0.f};

    const unsigned short* Abase = Xh + (size_t)m0 * DD;
    const unsigned short* Bbase = WT + (size_t)n0 * DD;

    // prologue: DMA tile 0 into buffer 0
#pragma unroll
    for (int p = 0; p < 4; p++) {
        gload_lds16(Abase + g_off[p], &As[0][(p * 4 + w) * 512]);
        gload_lds16(Bbase + g_off[p], &Bs[0][(p * 4 + w) * 512]);
    }

    for (int it = 0; it < NKT; it++) {
        const int cur = it & 1;
        __syncthreads();   // drains DMA(it); all waves done reading buf[cur^1]
        if (it + 1 < NKT) {
            const int kt2 = (it + 1) * GBK;
#pragma unroll
            for (int p = 0; p < 4; p++) {
                gload_lds16(Abase + g_off[p] + kt2, &As[cur ^ 1][(p * 4 + w) * 512]);
                gload_lds16(Bbase + g_off[p] + kt2, &Bs[cur ^ 1][(p * 4 + w) * 512]);
            }
        }
#pragma unroll
        for (int ks = 0; ks < 2; ks++) {
            f16x8 af[4], bf[4];
#pragma unroll
            for (int i = 0; i < 4; i++) {
                af[i] = *(const f16x8*)&As[cur][((wm * 4 + i) * 2 + ks) * 512 + lane * 8];
                bf[i] = *(const f16x8*)&Bs[cur][((wn * 4 + i) * 2 + ks) * 512 + lane * 8];
            }
#pragma unroll
            for (int ns = 0; ns < 4; ns++)
#pragma unroll
                for (int ms = 0; ms < 4; ms++)
                    acc[ms][ns] = __builtin_amdgcn_mfma_f32_16x16x32_f16(
                        af[ms], bf[ns], acc[ms][ns], 0, 0, 0);
        }
    }

    // epilogue: bias + fp16; q linear [B,H,S,HD]; k AND v pre-swizzled tiles
    // (v transposed: offset(key,e) = tile*4096 + swz(e, key>>3) + (key&7)).
    const int sel = n0 >> 10;
    const int hw = ((n0 + wn * 64) >> 6) & 15;
    const int bblk = m0 >> 11;
    const float* bias = (sel == 0) ? bq : ((sel == 1) ? bk : bv);
    const size_t bh_base = ((size_t)bblk * HH + hw) * SS * HD;
    float wmx = 0.0f;
#pragma unroll
    for (int ms = 0; ms < 4; ms++) {
#pragma unroll
        for (int rr = 0; rr < 4; rr++) {
            const int m = m0 + wm * 64 + ms * 16 + quad * 4 + rr;
            const int s = m & (SS - 1);
            const int s63 = s & 63;
            float v2 = 0.0f;
#pragma unroll
            for (int ns = 0; ns < 4; ns++) {
                const int e = ns * 16 + l15;
                const float val = acc[ms][ns][rr] + bias[hw * HD + e];
                if (sel == 0) {
                    qh[bh_base + (size_t)s * HD + e] = hbits((_Float16)val);
                } else if (sel == 1) {
                    v2 = fmaf(val, val, v2);
                    const size_t kofs = bh_base + (size_t)(s >> 6) * 4096
                                      + swz(s63, e >> 3) + (e & 7);
                    kh[kofs] = hbits((_Float16)val);
                } else {
                    const size_t vofs = bh_base + (size_t)(s >> 6) * 4096
                                      + swz(e, s63 >> 3) + (s63 & 7);
                    vTs[vofs] = hbits((_Float16)val);
                }
            }
            if (sel == 1) {
                v2 += __shfl_xor(v2, 1);
                v2 += __shfl_xor(v2, 2);
                v2 += __shfl_xor(v2, 4);
                v2 += __shfl_xor(v2, 8);
                wmx = fmaxf(wmx, v2);
            }
        }
    }
    if (sel == 1) {
        wmx = fmaxf(wmx, __shfl_xor(wmx, 16));
        wmx = fmaxf(wmx, __shfl_xor(wmx, 32));
        if (lane == 0)
            atomicMax(&kc2[bblk * HH + hw], __float_as_uint(wmx));
    }
}

__global__ __launch_bounds__(256) void out_gemm(
    const unsigned short* __restrict__ Ctxh, const unsigned short* __restrict__ WoT,
    const float* __restrict__ bo, float* __restrict__ out)
{
    __shared__ __align__(16) unsigned short As[2][16 * 512];
    __shared__ __align__(16) unsigned short Bs[2][16 * 512];

    const int tid = threadIdx.x;
    const int m0 = blockIdx.y * GBM;
    const int n0 = blockIdx.x * GBN;
    const int lane = tid & 63;
    const int w = tid >> 6;
    const int wm = w & 1, wn = w >> 1;
    const int l15 = lane & 15, quad = lane >> 4;

    int g_off[4];
#pragma unroll
    for (int p = 0; p < 4; p++) {
        const int c = p * 4 + w;
        g_off[p] = ((c >> 1) * 16 + (lane & 15)) * DD + (c & 1) * 32 + (lane >> 4) * 8;
    }

    f32x4 acc[4][4];
#pragma unroll
    for (int i = 0; i < 4; i++)
#pragma unroll
        for (int j = 0; j < 4; j++) acc[i][j] = (f32x4){0.f, 0.f, 0.f, 0.f};

    const unsigned short* Abase = Ctxh + (size_t)m0 * DD;
    const unsigned short* Bbase = WoT + (size_t)n0 * DD;

#pragma unroll
    for (int p = 0; p < 4; p++) {
        gload_lds16(Abase + g_off[p], &As[0][(p * 4 + w) * 512]);
        gload_lds16(Bbase + g_off[p], &Bs[0][(p * 4 + w) * 512]);
    }

    for (int it = 0; it < NKT; it++) {
        const int cur = it & 1;
        __syncthreads();
        if (it + 1 < NKT) {
            const int kt2 = (it + 1) * GBK;
#pragma unroll
            for (int p = 0; p < 4; p++) {
                gload_lds16(Abase + g_off[p] + kt2, &As[cur ^ 1][(p * 4 + w) * 512]);
                gload_lds16(Bbase + g_off[p] + kt2, &Bs[cur ^ 1][(p * 4 + w) * 512]);
            }
        }
#pragma unroll
        for (int ks = 0; ks < 2; ks++) {
            f16x8 af[4], bf[4];
#pragma unroll
            for (int i = 0; i < 4; i++) {
                af[i] = *(const f16x8*)&As[cur][((wm * 4 + i) * 2 + ks) * 512 + lane * 8];
                bf[i] = *(const f16x8*)&Bs[cur][((wn * 4 + i) * 2 + ks) * 512 + lane * 8];
            }
#pragma unroll
            for (int ns = 0; ns < 4; ns++)
#pragma unroll
                for (int ms = 0; ms < 4; ms++)
                    acc[ms][ns] = __builtin_amdgcn_mfma_f32_16x16x32_f16(
                        af[ms], bf[ns], acc[ms][ns], 0, 0, 0);
        }
    }

#pragma unroll
    for (int ms = 0; ms < 4; ms++) {
#pragma unroll
        for (int rr = 0; rr < 4; rr++) {
            const size_t m = (size_t)(m0 + wm * 64 + ms * 16 + quad * 4 + rr);
#pragma unroll
            for (int ns = 0; ns < 4; ns++) {
                const int n = n0 + wn * 64 + ns * 16 + l15;
                out[m * DD + n] = acc[ms][ns][rr] + bo[n];
            }
        }
    }
}

// ---------------------------------------------------------------------------
// fp16 MFMA flash attention (S^T), fixed-m softmax, DOUBLE-BUFFERED DMA from
// pre-swizzled K / V^T global tiles (one barrier per tile), l via ones-MFMA.
// ---------------------------------------------------------------------------
#define TQB 128
#define TKB 64
#define NT (SS / TKB)    // 32
#define C1 0.1803368801111204f   // 0.125 * log2(e)

__global__ __launch_bounds__(256) void attn_mfma(
    const unsigned short* __restrict__ qh, const unsigned short* __restrict__ kh,
    const unsigned short* __restrict__ vTs, const unsigned int* __restrict__ kc2,
    unsigned short* __restrict__ ctxh)
{
    __shared__ __align__(16) unsigned short KL [2][TKB * 64];
    __shared__ __align__(16) unsigned short VtL[2][HD * 64];
    __shared__ __align__(16) unsigned short PsL[4][32 * 64];

    const int tid  = threadIdx.x;
    const int lane = tid & 63;
    const int w    = tid >> 6;
    const int l15  = lane & 15;
    const int quad = lane >> 4;
    const int bh   = blockIdx.y;
    const int q0   = blockIdx.x * TQB;

    const float kfac = sqrtf(__uint_as_float(kc2[bh])) * 1.01f * C1;

    // Q B-frags (lane l15 = q-row, quad = d-octet) + per-lane fixed-m bound
    f16x8 qf[2][2];
    float M2[2];
#pragma unroll
    for (int msub = 0; msub < 2; msub++) {
        const unsigned short* qrow =
            qh + ((size_t)bh * SS + q0 + w * 32 + msub * 16 + l15) * HD;
        float nq2 = 0.0f;
#pragma unroll
        for (int dstep = 0; dstep < 2; dstep++) {
            qf[msub][dstep] = *(const f16x8*)&qrow[dstep * 32 + quad * 8];
#pragma unroll
            for (int j = 0; j < 8; j++) {
                const float x = (float)qf[msub][dstep][j];
                nq2 = fmaf(x, x, nq2);
            }
        }
        nq2 += __shfl_xor(nq2, 16);
        nq2 += __shfl_xor(nq2, 32);
        M2[msub] = sqrtf(nq2) * kfac;
    }

    f16x8 ones;
#pragma unroll
    for (int j = 0; j < 8; j++) ones[j] = (_Float16)1.0f;

    f32x4 o[2][4], lones[2];
#pragma unroll
    for (int ms = 0; ms < 2; ms++) {
        lones[ms] = (f32x4){0.f, 0.f, 0.f, 0.f};
#pragma unroll
        for (int e = 0; e < 4; e++) o[ms][e] = (f32x4){0.f, 0.f, 0.f, 0.f};
    }

    const unsigned short* kb0 = kh  + (size_t)bh * SS * HD;
    const unsigned short* vb0 = vTs + (size_t)bh * SS * HD;

    // prologue: DMA tile 0 into buffer 0
    gload_lds16(kb0 + tid * 8,        &KL [0][w * 512]);
    gload_lds16(kb0 + 2048 + tid * 8, &KL [0][2048 + w * 512]);
    gload_lds16(vb0 + tid * 8,        &VtL[0][w * 512]);
    gload_lds16(vb0 + 2048 + tid * 8, &VtL[0][2048 + w * 512]);

    for (int t = 0; t < NT; t++) {
        const int cur = t & 1;
        __syncthreads();   // drains DMA(t); all waves done with buf[cur^1]
        if (t + 1 < NT) {
            const unsigned short* kb = kb0 + (size_t)(t + 1) * 4096;
            const unsigned short* vb = vb0 + (size_t)(t + 1) * 4096;
            gload_lds16(kb + tid * 8,        &KL [cur ^ 1][w * 512]);
            gload_lds16(kb + 2048 + tid * 8, &KL [cur ^ 1][2048 + w * 512]);
            gload_lds16(vb + tid * 8,        &VtL[cur ^ 1][w * 512]);
            gload_lds16(vb + 2048 + tid * 8, &VtL[cur ^ 1][2048 + w * 512]);
        }

        // ---- scores TRANSPOSED: S^T = K·Q^T; C/D row = key, col = q = l15
        f32x4 sc[2][4];
#pragma unroll
        for (int ksub = 0; ksub < 4; ksub++) {
            const int row = ksub * 16 + l15;
            f16x8 k0 = *(const f16x8*)&KL[cur][swz(row, quad)];
            f16x8 k1 = *(const f16x8*)&KL[cur][swz(row, 4 + quad)];
#pragma unroll
            for (int msub = 0; msub < 2; msub++) {
                f32x4 a = (f32x4){0.f, 0.f, 0.f, 0.f};
                a = __builtin_amdgcn_mfma_f32_16x16x32_f16(k0, qf[msub][0], a, 0, 0, 0);
                a = __builtin_amdgcn_mfma_f32_16x16x32_f16(k1, qf[msub][1], a, 0, 0, 0);
                sc[msub][ksub] = a;
            }
        }

        // ---- fixed-m softmax (per-lane q = l15), packed f16 P
#pragma unroll
        for (int msub = 0; msub < 2; msub++) {
            const int prow = msub * 16 + l15;
#pragma unroll
            for (int ksub = 0; ksub < 4; ksub++) {
                const float p0 = fexp2(fmaf(sc[msub][ksub][0], C1, -M2[msub]));
                const float p1 = fexp2(fmaf(sc[msub][ksub][1], C1, -M2[msub]));
                const float p2 = fexp2(fmaf(sc[msub][ksub][2], C1, -M2[msub]));
                const float p3 = fexp2(fmaf(sc[msub][ksub][3], C1, -M2[msub]));
                *(u16x4*)&PsL[w][swz(prow, ksub * 2 + (quad >> 1)) + (quad & 1) * 4] =
                    pack4(p0, p1, p2, p3);
            }
        }

        // ---- PV + l via ones-MFMA (PsL wave-private: no barrier)
#pragma unroll
        for (int kj = 0; kj < 2; kj++) {
            f16x8 pa[2];
#pragma unroll
            for (int msub = 0; msub < 2; msub++)
                pa[msub] = *(const f16x8*)&PsL[w][swz(msub * 16 + l15, kj * 4 + quad)];
            lones[0] = __builtin_amdgcn_mfma_f32_16x16x32_f16(pa[0], ones, lones[0], 0, 0, 0);
            lones[1] = __builtin_amdgcn_mfma_f32_16x16x32_f16(pa[1], ones, lones[1], 0, 0, 0);
#pragma unroll
            for (int esub = 0; esub < 4; esub++) {
                f16x8 vr = *(const f16x8*)&VtL[cur][swz(esub * 16 + l15, kj * 4 + quad)];
                o[0][esub] = __builtin_amdgcn_mfma_f32_16x16x32_f16(pa[0], vr, o[0][esub], 0, 0, 0);
                o[1][esub] = __builtin_amdgcn_mfma_f32_16x16x32_f16(pa[1], vr, o[1][esub], 0, 0, 0);
            }
        }
    }

    // ---- epilogue: l sits in the same C-layout rows as o — no shuffles
    const int b = bh >> 4;
    const int h = bh & 15;
#pragma unroll
    for (int msub = 0; msub < 2; msub++) {
#pragma unroll
        for (int rr = 0; rr < 4; rr++) {
            const float linv = 1.0f / lones[msub][rr];
            const int row = q0 + w * 32 + msub * 16 + quad * 4 + rr;
#pragma unroll
            for (int esub = 0; esub < 4; esub++) {
                ctxh[((size_t)b * SS + row) * DD + h * HD + esub * 16 + l15] =
                    hbits((_Float16)(o[msub][esub][rr] * linv));
            }
        }
    }
}

// ---------------------------------------------------------------------------
extern "C" void kernel_launch(void* const* d_in, const int* in_sizes, int n_in,
                              void* d_out, int out_size, void* d_ws, size_t ws_size,
                              hipStream_t stream) {
    const float* X  = (const float*)d_in[0];
    const float* Wq = (const float*)d_in[1];
    const float* bq = (const float*)d_in[2];
    const float* Wk = (const float*)d_in[3];
    const float* bk = (const float*)d_in[4];
    const float* Wv = (const float*)d_in[5];
    const float* bv = (const float*)d_in[6];
    const float* Wo = (const float*)d_in[7];
    const float* bo = (const float*)d_in[8];
    float* out = (float*)d_out;

    // ws: Xh | WT(4096 rows) | qh | kh(swz) | vTs(swz) | ctxh | kc2
    const size_t NB2 = (size_t)4096 * 1024 * 2;   // 8388608 B
    unsigned char* w8 = (unsigned char*)d_ws;
    unsigned short* Xh   = (unsigned short*)(w8);
    unsigned short* WT   = (unsigned short*)(w8 + NB2);
    unsigned short* qh   = (unsigned short*)(w8 + 2 * NB2);
    unsigned short* kh   = (unsigned short*)(w8 + 3 * NB2);
    unsigned short* vTs  = (unsigned short*)(w8 + 4 * NB2);
    unsigned short* ctxh = (unsigned short*)(w8 + 5 * NB2);
    unsigned int*   kc2  = (unsigned int*)(w8 + 6 * NB2);
    unsigned short* WoT  = WT + (size_t)3072 * 1024;

    (void)hipMemsetAsync(kc2, 0, BB * HH * sizeof(unsigned int), stream);

    // 0) convert X + transpose/convert weights to fp16
    prep_convert<<<dim3(3072), 256, 0, stream>>>(X, Wq, Wk, Wv, Wo, Xh, WT);

    // 1) fused QKV projection (fp16 MFMA, dbuf DMA; writes V^T directly)
    qkv_gemm<<<dim3(3072 / GBN, 4096 / GBM), 256, 0, stream>>>(
        Xh, WT, bq, bk, bv, qh, kh, vTs, kc2);

    // 2) MFMA flash attention (S^T, fixed-m softmax, dbuf DMA)
    attn_mfma<<<dim3(SS / TQB, BB * HH), 256, 0, stream>>>(qh, kh, vTs, kc2, ctxh);

    // 3) output projection (fp16 MFMA, dbuf DMA)
    out_gemm<<<dim3(1024 / GBN, 4096 / GBM), 256, 0, stream>>>(ctxh, WoT, bo, out);
}